// Round 2
// baseline (2353.761 us; speedup 1.0000x reference)
//
#include <hip/hip_runtime.h>

#define CDIV(a, b) (((a) + (b) - 1) / (b))

// Native fp32 atomic add (ds_add_f32 / global_atomic_add_f32).
// Plain atomicAdd(float*) lowers to a CAS loop (~90 cy/op on LDS) without
// unsafe-fp-atomics; this was the entire splat bottleneck (394 us @ 3% VALU).
__device__ __forceinline__ void fadd_native(float* p, float v) {
    unsafeAtomicAdd(p, v);
}

// ---------------------------------------------------------------------------
// Tiled conv 3x3 pad 1 stride {1,2} + bias + PReLU.
// 256 threads -> TSxTS output tile, KO=8 output channels in registers,
// each thread computes (TS/16)^2 pixels. Input plane staged per-ci in LDS.
// ---------------------------------------------------------------------------
template <int STRIDE, int TS>
__global__ __launch_bounds__(256)
void conv3x3_tile_kernel(const float* __restrict__ in,
                         const float* __restrict__ wgt,
                         const float* __restrict__ bias,
                         const float* __restrict__ alpha,
                         float* __restrict__ out,
                         int Ci, int Hi, int Wi, int Co, int Ho, int Wo,
                         int nTX) {
    constexpr int PB = TS / 16;               // pixels per thread per dim
    constexpr int IS = TS * STRIDE + 2;       // input tile side
    constexpr int KO = 8;
    constexpr int SP = (PB - 1) * STRIDE + 3; // per-thread tap span
    __shared__ float s_in[IS * IS];
    __shared__ float s_w[KO * 12];

    const int b   = blockIdx.z;
    const int co0 = blockIdx.y * KO;
    const int tX  = (blockIdx.x % nTX) * TS;
    const int tY  = (blockIdx.x / nTX) * TS;
    const int t   = threadIdx.x;
    const int tcx = t & 15, tcy = t >> 4;
    const int ox0 = PB * tcx, oy0 = PB * tcy;

    float acc[KO][PB][PB];
#pragma unroll
    for (int ko = 0; ko < KO; ++ko)
#pragma unroll
        for (int dy = 0; dy < PB; ++dy)
#pragma unroll
            for (int dx = 0; dx < PB; ++dx) acc[ko][dy][dx] = 0.f;

    const float* inb = in + (size_t)b * Ci * Hi * Wi;
    const int ix0 = tX * STRIDE - 1, iy0 = tY * STRIDE - 1;

    for (int ci = 0; ci < Ci; ++ci) {
        __syncthreads();
        const float* inp = inb + (size_t)ci * Hi * Wi;
        for (int i = t; i < IS * IS; i += 256) {
            const int r = i / IS, c = i - r * IS;
            const int gy = iy0 + r, gx = ix0 + c;
            float v = 0.f;
            if (gy >= 0 && gy < Hi && gx >= 0 && gx < Wi)
                v = inp[(size_t)gy * Wi + gx];
            s_in[i] = v;
        }
        if (t < KO * 9) {
            const int ko = t / 9, k = t - ko * 9;
            s_w[ko * 12 + k] = wgt[((size_t)(co0 + ko) * Ci + ci) * 9 + k];
        }
        __syncthreads();

        float tap[SP][SP];
#pragma unroll
        for (int r = 0; r < SP; ++r)
#pragma unroll
            for (int c = 0; c < SP; ++c)
                tap[r][c] = s_in[(oy0 * STRIDE + r) * IS + ox0 * STRIDE + c];

#pragma unroll
        for (int ko = 0; ko < KO; ++ko) {
            float w[9];
#pragma unroll
            for (int k = 0; k < 9; ++k) w[k] = s_w[ko * 12 + k];
#pragma unroll
            for (int dy = 0; dy < PB; ++dy)
#pragma unroll
                for (int dx = 0; dx < PB; ++dx) {
                    float a = acc[ko][dy][dx];
#pragma unroll
                    for (int ky = 0; ky < 3; ++ky)
#pragma unroll
                        for (int kx = 0; kx < 3; ++kx)
                            a += tap[dy * STRIDE + ky][dx * STRIDE + kx] *
                                 w[ky * 3 + kx];
                    acc[ko][dy][dx] = a;
                }
        }
    }

#pragma unroll
    for (int ko = 0; ko < KO; ++ko) {
        const int co = co0 + ko;
        const float bv = bias[co], av = alpha[co];
#pragma unroll
        for (int dy = 0; dy < PB; ++dy) {
            const int oy = tY + oy0 + dy;
#pragma unroll
            for (int dx = 0; dx < PB; ++dx) {
                const int ox = tX + ox0 + dx;
                float v = acc[ko][dy][dx] + bv;
                v = v >= 0.f ? v : av * v;
                out[(((size_t)b * Co + co) * Ho + oy) * Wo + ox] = v;
            }
        }
    }
}

// ---------------------------------------------------------------------------
// flow halving: 2x2 mean * 0.5 == sum * 0.125
// ---------------------------------------------------------------------------
__global__ void halve_flow_kernel(const float* __restrict__ in,
                                  float* __restrict__ out,
                                  int BC, int Ho, int Wo, int Hi, int Wi) {
    const int idx = blockIdx.x * blockDim.x + threadIdx.x;
    const int total = BC * Ho * Wo;
    if (idx >= total) return;
    const int wo = idx % Wo;
    int t = idx / Wo;
    const int ho = t % Ho;
    const int bc = t / Ho;
    const float* p = in + ((size_t)bc * Hi + 2 * ho) * Wi + 2 * wo;
    out[idx] = (p[0] + p[1] + p[Wi] + p[Wi + 1]) * 0.125f;
}

// ---------------------------------------------------------------------------
// Outlier splat pre-pass: sources with |flow| > thr (statistically ~never for
// this input) are splatted with device atomics into the num/cnt overlay.
// Sets *flag so the owner-tile kernel knows to read the overlay.
// thr MUST equal (float)(RP-1) of the matching owner kernel.
// ---------------------------------------------------------------------------
__global__ void splat_outlier_kernel(const float* __restrict__ feat,
                                     const float* __restrict__ flow,
                                     float* __restrict__ num,
                                     float* __restrict__ cnt,
                                     int* __restrict__ flag,
                                     int B, int C, int H, int W, float thr) {
    const int HW = H * W;
    const int idx = blockIdx.x * blockDim.x + threadIdx.x;
    if (idx >= B * HW) return;
    const int b = idx / HW, px = idx - b * HW;
    const int y = px / W, x = px - y * W;
    const float dx = flow[(size_t)b * 2 * HW + px];
    const float dy = flow[(size_t)b * 2 * HW + HW + px];
    if (fabsf(dx) <= thr && fabsf(dy) <= thr) return;   // fast-path source
    atomicAdd(flag, 1);
    const float fx = dx + (float)x, fy = dy + (float)y;
    const float x0f = floorf(fx), y0f = floorf(fy);
    const int x0 = (int)x0f, y0 = (int)y0f;
    const float ax = fx - x0f, ay = fy - y0f;
    const float w[4] = {(1.f - ax) * (1.f - ay), ax * (1.f - ay),
                        (1.f - ax) * ay,         ax * ay};
    const int cx[4] = {x0, x0 + 1, x0, x0 + 1};
    const int cy[4] = {y0, y0, y0 + 1, y0 + 1};
    float* cb = cnt + (size_t)b * HW;
    for (int k = 0; k < 4; ++k) {
        if (cx[k] < 0 || cx[k] >= W || cy[k] < 0 || cy[k] >= H) continue;
        if (w[k] == 0.f) continue;
        const size_t d = (size_t)cy[k] * W + cx[k];
        fadd_native(cb + d, w[k]);
        for (int c = 0; c < C; ++c)
            fadd_native(num + ((size_t)b * C + c) * HW + d,
                        feat[((size_t)b * C + c) * HW + px] * w[k]);
    }
}

// ---------------------------------------------------------------------------
// Owner-tile splat: each block exclusively owns a TS x TS destination tile.
// It scans the source window [t0-RP, t0+TS+RP), accumulates the bilinear
// corners that land in its interior into LDS (feat channels + cnt), then
// divides and writes the final average with PLAIN coalesced stores.
// No global atomics on the fast path. Sources with |flow| > RP-1 are skipped
// here (handled exactly by splat_outlier_kernel; overlay is added iff *oflag).
// LDS accumulation uses NATIVE ds_add_f32 via unsafeAtomicAdd.
// ---------------------------------------------------------------------------
template <int TS, int RP, int NCH>
__global__ __launch_bounds__(256)
void splat_owner_kernel(const float* __restrict__ feat,
                        const float* __restrict__ flow,
                        const float* __restrict__ cnt_ov,
                        const int* __restrict__ oflag,
                        float* __restrict__ out,
                        int C, int H, int W, int nTX) {
    constexpr int WS = TS + 2 * RP;     // source window side
    constexpr int NSRC = WS * WS;
    constexpr float THR = (float)(RP - 1);
    __shared__ float s_num[NCH][TS * TS];
    __shared__ float s_cnt[TS * TS];

    const int b   = blockIdx.z;
    const int c0  = blockIdx.y * NCH;
    const int tx0 = (blockIdx.x % nTX) * TS;
    const int ty0 = (blockIdx.x / nTX) * TS;
    const int t   = threadIdx.x;
    const int HW  = H * W;
    const float* flx = flow + (size_t)b * 2 * HW;
    const float* fly = flx + HW;
    const float* fb  = feat + ((size_t)b * C + c0) * HW;

    for (int i = t; i < TS * TS; i += 256) {
        s_cnt[i] = 0.f;
#pragma unroll
        for (int ch = 0; ch < NCH; ++ch) s_num[ch][i] = 0.f;
    }
    __syncthreads();

    for (int sp = t; sp < NSRC; sp += 256) {
        const int wy = sp / WS, wx = sp - wy * WS;
        const int y = ty0 - RP + wy, x = tx0 - RP + wx;
        if (y < 0 || y >= H || x < 0 || x >= W) continue;
        const float dx = flx[(size_t)y * W + x];
        const float dy = fly[(size_t)y * W + x];
        if (fabsf(dx) > THR || fabsf(dy) > THR) continue;  // outlier pre-pass
        const float fx = dx + (float)x, fy = dy + (float)y;
        const float x0f = floorf(fx), y0f = floorf(fy);
        const int x0 = (int)x0f, y0 = (int)y0f;
        const float ax = fx - x0f, ay = fy - y0f;
        const float w00 = (1.f - ax) * (1.f - ay);
        const float w10 = ax * (1.f - ay);
        const float w01 = (1.f - ax) * ay;
        const float w11 = ax * ay;
        // interior ownership (interior cells are in-image by construction)
        const int lx0 = x0 - tx0, ly0 = y0 - ty0;
        const bool inx0 = (lx0 >= 0) & (lx0 < TS);
        const bool inx1 = (lx0 + 1 >= 0) & (lx0 + 1 < TS);
        const bool iny0 = (ly0 >= 0) & (ly0 < TS);
        const bool iny1 = (ly0 + 1 >= 0) & (ly0 + 1 < TS);
        const bool in00 = inx0 & iny0, in10 = inx1 & iny0;
        const bool in01 = inx0 & iny1, in11 = inx1 & iny1;
        if (!(in00 | in10 | in01 | in11)) continue;

        float f[NCH];
        const float* fp = fb + (size_t)y * W + x;
#pragma unroll
        for (int ch = 0; ch < NCH; ++ch) f[ch] = fp[(size_t)ch * HW];

        const int cell = ly0 * TS + lx0;
        if (in00) {
            fadd_native(&s_cnt[cell], w00);
#pragma unroll
            for (int ch = 0; ch < NCH; ++ch)
                fadd_native(&s_num[ch][cell], f[ch] * w00);
        }
        if (in10) {
            fadd_native(&s_cnt[cell + 1], w10);
#pragma unroll
            for (int ch = 0; ch < NCH; ++ch)
                fadd_native(&s_num[ch][cell + 1], f[ch] * w10);
        }
        if (in01) {
            fadd_native(&s_cnt[cell + TS], w01);
#pragma unroll
            for (int ch = 0; ch < NCH; ++ch)
                fadd_native(&s_num[ch][cell + TS], f[ch] * w01);
        }
        if (in11) {
            fadd_native(&s_cnt[cell + TS + 1], w11);
#pragma unroll
            for (int ch = 0; ch < NCH; ++ch)
                fadd_native(&s_num[ch][cell + TS + 1], f[ch] * w11);
        }
    }
    __syncthreads();

    const int has = *oflag;   // uniform: overlay only if outliers existed
    for (int i = t; i < TS * TS; i += 256) {
        const int ly = i / TS, lx = i - ly * TS;
        const size_t px = (size_t)(ty0 + ly) * W + (tx0 + lx);
        float cv = s_cnt[i];
        if (has) cv += cnt_ov[(size_t)b * HW + px];
        const float denom = (cv == 0.f) ? 1.f : cv;
        const float inv = 1.f / denom;
#pragma unroll
        for (int ch = 0; ch < NCH; ++ch) {
            float v = s_num[ch][i];
            const size_t go = ((size_t)b * C + c0 + ch) * HW + px;
            if (has) v += out[go];
            out[go] = v * inv;
        }
    }
}

extern "C" void kernel_launch(void* const* d_in, const int* in_sizes, int n_in,
                              void* d_out, int out_size, void* d_ws, size_t ws_size,
                              hipStream_t stream) {
    (void)in_sizes; (void)n_in; (void)ws_size;

    const float* img  = (const float*)d_in[0];
    const float* flow = (const float*)d_in[1];
    const float* P[4][6];
    for (int i = 0; i < 4; ++i)
        for (int j = 0; j < 6; ++j)
            P[i][j] = (const float*)d_in[2 + 6 * i + j];

    const int Bn = 16;
    float* ws = (float*)d_ws;
    float* bufA = ws;                       // 16M floats
    float* bufB = ws + 16777216;            // 16M floats
    float* flA  = ws + 33554432;            // 2M floats
    float* flB  = ws + 35651584;            // 512K floats
    float* cnt  = ws + 36175872;            // 1M floats (outlier cnt overlay)
    int*   flag = (int*)(ws + 37224448);    // outlier-present flag
    float* out  = (float*)d_out;

    hipMemsetAsync(d_out, 0, (size_t)out_size * sizeof(float), stream);

    auto conv = [&](const float* in, const float* w, const float* b,
                    const float* a, float* o, int Ci, int Hi, int Wi,
                    int Co, int stride) {
        const int Ho = Hi / stride, Wo = Wi / stride;
        const int TS = (Wo >= 128) ? 32 : 16;
        const int nTX = Wo / TS, nTY = Ho / TS;
        dim3 grid(nTX * nTY, Co / 8, Bn);
        if (stride == 1) {
            if (TS == 32)
                hipLaunchKernelGGL((conv3x3_tile_kernel<1, 32>), grid, dim3(256), 0,
                                   stream, in, w, b, a, o, Ci, Hi, Wi, Co, Ho, Wo, nTX);
            else
                hipLaunchKernelGGL((conv3x3_tile_kernel<1, 16>), grid, dim3(256), 0,
                                   stream, in, w, b, a, o, Ci, Hi, Wi, Co, Ho, Wo, nTX);
        } else {
            if (TS == 32)
                hipLaunchKernelGGL((conv3x3_tile_kernel<2, 32>), grid, dim3(256), 0,
                                   stream, in, w, b, a, o, Ci, Hi, Wi, Co, Ho, Wo, nTX);
            else
                hipLaunchKernelGGL((conv3x3_tile_kernel<2, 16>), grid, dim3(256), 0,
                                   stream, in, w, b, a, o, Ci, Hi, Wi, Co, Ho, Wo, nTX);
        }
    };
    auto halve = [&](const float* in, float* o, int Hi, int Wi) {
        const int Ho = Hi / 2, Wo = Wi / 2;
        const int total = Bn * 2 * Ho * Wo;
        hipLaunchKernelGGL(halve_flow_kernel, dim3(CDIV(total, 256)), dim3(256),
                           0, stream, in, o, Bn * 2, Ho, Wo, Hi, Wi);
    };

    float* p1 = out;
    float* p2 = p1 + (size_t)Bn * 16 * 256 * 256;
    float* p3 = p2 + (size_t)Bn * 32 * 128 * 128;
    float* p4 = p3 + (size_t)Bn * 64 * 64 * 64;

    // ---- level 1
    conv(img,  P[0][0], P[0][1], P[0][2], bufA, 3, 512, 512, 16, 2);
    conv(bufA, P[0][3], P[0][4], P[0][5], bufB, 16, 256, 256, 16, 1);
    halve(flow, flA, 512, 512);
    {
        const int C = 16, H = 256, W = 256;
        hipMemsetAsync(cnt, 0, (size_t)Bn * H * W * sizeof(float), stream);
        hipMemsetAsync(flag, 0, sizeof(int), stream);
        hipLaunchKernelGGL(splat_outlier_kernel, dim3(CDIV(Bn * H * W, 256)),
                           dim3(256), 0, stream, bufB, flA, p1, cnt, flag,
                           Bn, C, H, W, 7.f);
        hipLaunchKernelGGL((splat_owner_kernel<32, 8, 8>),
                           dim3((W / 32) * (H / 32), C / 8, Bn), dim3(256), 0,
                           stream, bufB, flA, cnt, flag, p1, C, H, W, W / 32);
    }

    // ---- level 2
    conv(bufB, P[1][0], P[1][1], P[1][2], bufA, 16, 256, 256, 32, 2);
    conv(bufA, P[1][3], P[1][4], P[1][5], bufB, 32, 128, 128, 32, 1);
    halve(flA, flB, 256, 256);
    {
        const int C = 32, H = 128, W = 128;
        hipMemsetAsync(cnt, 0, (size_t)Bn * H * W * sizeof(float), stream);
        hipMemsetAsync(flag, 0, sizeof(int), stream);
        hipLaunchKernelGGL(splat_outlier_kernel, dim3(CDIV(Bn * H * W, 256)),
                           dim3(256), 0, stream, bufB, flB, p2, cnt, flag,
                           Bn, C, H, W, 3.f);
        hipLaunchKernelGGL((splat_owner_kernel<32, 4, 8>),
                           dim3((W / 32) * (H / 32), C / 8, Bn), dim3(256), 0,
                           stream, bufB, flB, cnt, flag, p2, C, H, W, W / 32);
    }

    // ---- level 3
    conv(bufB, P[2][0], P[2][1], P[2][2], bufA, 32, 128, 128, 64, 2);
    conv(bufA, P[2][3], P[2][4], P[2][5], bufB, 64, 64, 64, 64, 1);
    halve(flB, flA, 128, 128);
    {
        const int C = 64, H = 64, W = 64;
        hipMemsetAsync(cnt, 0, (size_t)Bn * H * W * sizeof(float), stream);
        hipMemsetAsync(flag, 0, sizeof(int), stream);
        hipLaunchKernelGGL(splat_outlier_kernel, dim3(CDIV(Bn * H * W, 256)),
                           dim3(256), 0, stream, bufB, flA, p3, cnt, flag,
                           Bn, C, H, W, 2.f);
        hipLaunchKernelGGL((splat_owner_kernel<16, 3, 16>),
                           dim3((W / 16) * (H / 16), C / 16, Bn), dim3(256), 0,
                           stream, bufB, flA, cnt, flag, p3, C, H, W, W / 16);
    }

    // ---- level 4
    conv(bufB, P[3][0], P[3][1], P[3][2], bufA, 64, 64, 64, 128, 2);
    conv(bufA, P[3][3], P[3][4], P[3][5], bufB, 128, 32, 32, 128, 1);
    halve(flA, flB, 64, 64);
    {
        const int C = 128, H = 32, W = 32;
        hipMemsetAsync(cnt, 0, (size_t)Bn * H * W * sizeof(float), stream);
        hipMemsetAsync(flag, 0, sizeof(int), stream);
        hipLaunchKernelGGL(splat_outlier_kernel, dim3(CDIV(Bn * H * W, 256)),
                           dim3(256), 0, stream, bufB, flB, p4, cnt, flag,
                           Bn, C, H, W, 1.f);
        hipLaunchKernelGGL((splat_owner_kernel<16, 2, 16>),
                           dim3((W / 16) * (H / 16), C / 16, Bn), dim3(256), 0,
                           stream, bufB, flB, cnt, flag, p4, C, H, W, W / 16);
    }
}

// Round 3
// 2345.481 us; speedup vs baseline: 1.0035x; 1.0035x over previous
//
#include <hip/hip_runtime.h>

#define CDIV(a, b) (((a) + (b) - 1) / (b))

// Native fp32 atomic add for GLOBAL memory (outlier path only; ~never taken).
__device__ __forceinline__ void fadd_native(float* p, float v) {
    unsafeAtomicAdd(p, v);
}

// Native fp32 atomic add on LDS, forced via inline asm.
// atomicAdd/unsafeAtomicAdd on __shared__ float lowers to a ds_cmpst CAS loop
// (gated native selection) -> ~90 cy/add and 97% lgkmcnt stall; this emits the
// real ds_add_f32 (non-returning, fire-and-forget into the DS pipe).
// Generic LDS pointer = shared_aperture_hi32 | offset32, so the low 32 bits
// are the DS byte address.
__device__ __forceinline__ void lds_fadd(float* p, float v) {
    const uint32_t off = (uint32_t)(uintptr_t)p;
    asm volatile("ds_add_f32 %0, %1" :: "v"(off), "v"(v) : "memory");
}

// ---------------------------------------------------------------------------
// Tiled conv 3x3 pad 1 stride {1,2} + bias + PReLU.
// 256 threads -> TSxTS output tile, KO=8 output channels in registers,
// each thread computes (TS/16)^2 pixels. Input plane staged per-ci in LDS.
// ---------------------------------------------------------------------------
template <int STRIDE, int TS>
__global__ __launch_bounds__(256)
void conv3x3_tile_kernel(const float* __restrict__ in,
                         const float* __restrict__ wgt,
                         const float* __restrict__ bias,
                         const float* __restrict__ alpha,
                         float* __restrict__ out,
                         int Ci, int Hi, int Wi, int Co, int Ho, int Wo,
                         int nTX) {
    constexpr int PB = TS / 16;               // pixels per thread per dim
    constexpr int IS = TS * STRIDE + 2;       // input tile side
    constexpr int KO = 8;
    constexpr int SP = (PB - 1) * STRIDE + 3; // per-thread tap span
    __shared__ float s_in[IS * IS];
    __shared__ float s_w[KO * 12];

    const int b   = blockIdx.z;
    const int co0 = blockIdx.y * KO;
    const int tX  = (blockIdx.x % nTX) * TS;
    const int tY  = (blockIdx.x / nTX) * TS;
    const int t   = threadIdx.x;
    const int tcx = t & 15, tcy = t >> 4;
    const int ox0 = PB * tcx, oy0 = PB * tcy;

    float acc[KO][PB][PB];
#pragma unroll
    for (int ko = 0; ko < KO; ++ko)
#pragma unroll
        for (int dy = 0; dy < PB; ++dy)
#pragma unroll
            for (int dx = 0; dx < PB; ++dx) acc[ko][dy][dx] = 0.f;

    const float* inb = in + (size_t)b * Ci * Hi * Wi;
    const int ix0 = tX * STRIDE - 1, iy0 = tY * STRIDE - 1;

    for (int ci = 0; ci < Ci; ++ci) {
        __syncthreads();
        const float* inp = inb + (size_t)ci * Hi * Wi;
        for (int i = t; i < IS * IS; i += 256) {
            const int r = i / IS, c = i - r * IS;
            const int gy = iy0 + r, gx = ix0 + c;
            float v = 0.f;
            if (gy >= 0 && gy < Hi && gx >= 0 && gx < Wi)
                v = inp[(size_t)gy * Wi + gx];
            s_in[i] = v;
        }
        if (t < KO * 9) {
            const int ko = t / 9, k = t - ko * 9;
            s_w[ko * 12 + k] = wgt[((size_t)(co0 + ko) * Ci + ci) * 9 + k];
        }
        __syncthreads();

        float tap[SP][SP];
#pragma unroll
        for (int r = 0; r < SP; ++r)
#pragma unroll
            for (int c = 0; c < SP; ++c)
                tap[r][c] = s_in[(oy0 * STRIDE + r) * IS + ox0 * STRIDE + c];

#pragma unroll
        for (int ko = 0; ko < KO; ++ko) {
            float w[9];
#pragma unroll
            for (int k = 0; k < 9; ++k) w[k] = s_w[ko * 12 + k];
#pragma unroll
            for (int dy = 0; dy < PB; ++dy)
#pragma unroll
                for (int dx = 0; dx < PB; ++dx) {
                    float a = acc[ko][dy][dx];
#pragma unroll
                    for (int ky = 0; ky < 3; ++ky)
#pragma unroll
                        for (int kx = 0; kx < 3; ++kx)
                            a += tap[dy * STRIDE + ky][dx * STRIDE + kx] *
                                 w[ky * 3 + kx];
                    acc[ko][dy][dx] = a;
                }
        }
    }

#pragma unroll
    for (int ko = 0; ko < KO; ++ko) {
        const int co = co0 + ko;
        const float bv = bias[co], av = alpha[co];
#pragma unroll
        for (int dy = 0; dy < PB; ++dy) {
            const int oy = tY + oy0 + dy;
#pragma unroll
            for (int dx = 0; dx < PB; ++dx) {
                const int ox = tX + ox0 + dx;
                float v = acc[ko][dy][dx] + bv;
                v = v >= 0.f ? v : av * v;
                out[(((size_t)b * Co + co) * Ho + oy) * Wo + ox] = v;
            }
        }
    }
}

// ---------------------------------------------------------------------------
// flow halving: 2x2 mean * 0.5 == sum * 0.125
// ---------------------------------------------------------------------------
__global__ void halve_flow_kernel(const float* __restrict__ in,
                                  float* __restrict__ out,
                                  int BC, int Ho, int Wo, int Hi, int Wi) {
    const int idx = blockIdx.x * blockDim.x + threadIdx.x;
    const int total = BC * Ho * Wo;
    if (idx >= total) return;
    const int wo = idx % Wo;
    int t = idx / Wo;
    const int ho = t % Ho;
    const int bc = t / Ho;
    const float* p = in + ((size_t)bc * Hi + 2 * ho) * Wi + 2 * wo;
    out[idx] = (p[0] + p[1] + p[Wi] + p[Wi + 1]) * 0.125f;
}

// ---------------------------------------------------------------------------
// Outlier splat pre-pass: sources with |flow| > thr (statistically ~never for
// this input) are splatted with device atomics into the num/cnt overlay.
// Sets *flag so the owner-tile kernel knows to read the overlay.
// thr MUST equal (float)(RP-1) of the matching owner kernel.
// ---------------------------------------------------------------------------
__global__ void splat_outlier_kernel(const float* __restrict__ feat,
                                     const float* __restrict__ flow,
                                     float* __restrict__ num,
                                     float* __restrict__ cnt,
                                     int* __restrict__ flag,
                                     int B, int C, int H, int W, float thr) {
    const int HW = H * W;
    const int idx = blockIdx.x * blockDim.x + threadIdx.x;
    if (idx >= B * HW) return;
    const int b = idx / HW, px = idx - b * HW;
    const int y = px / W, x = px - y * W;
    const float dx = flow[(size_t)b * 2 * HW + px];
    const float dy = flow[(size_t)b * 2 * HW + HW + px];
    if (fabsf(dx) <= thr && fabsf(dy) <= thr) return;   // fast-path source
    atomicAdd(flag, 1);
    const float fx = dx + (float)x, fy = dy + (float)y;
    const float x0f = floorf(fx), y0f = floorf(fy);
    const int x0 = (int)x0f, y0 = (int)y0f;
    const float ax = fx - x0f, ay = fy - y0f;
    const float w[4] = {(1.f - ax) * (1.f - ay), ax * (1.f - ay),
                        (1.f - ax) * ay,         ax * ay};
    const int cx[4] = {x0, x0 + 1, x0, x0 + 1};
    const int cy[4] = {y0, y0, y0 + 1, y0 + 1};
    float* cb = cnt + (size_t)b * HW;
    for (int k = 0; k < 4; ++k) {
        if (cx[k] < 0 || cx[k] >= W || cy[k] < 0 || cy[k] >= H) continue;
        if (w[k] == 0.f) continue;
        const size_t d = (size_t)cy[k] * W + cx[k];
        fadd_native(cb + d, w[k]);
        for (int c = 0; c < C; ++c)
            fadd_native(num + ((size_t)b * C + c) * HW + d,
                        feat[((size_t)b * C + c) * HW + px] * w[k]);
    }
}

// ---------------------------------------------------------------------------
// Owner-tile splat: each block exclusively owns a TS x TS destination tile.
// It scans the source window [t0-RP, t0+TS+RP), accumulates the bilinear
// corners that land in its interior into LDS (feat channels + cnt), then
// divides and writes the final average with PLAIN coalesced stores.
// No global atomics on the fast path. Sources with |flow| > RP-1 are skipped
// here (handled exactly by splat_outlier_kernel; overlay is added iff *oflag).
// LDS accumulation: inline-asm ds_add_f32 (native, non-returning).
// ---------------------------------------------------------------------------
template <int TS, int RP, int NCH>
__global__ __launch_bounds__(256)
void splat_owner_kernel(const float* __restrict__ feat,
                        const float* __restrict__ flow,
                        const float* __restrict__ cnt_ov,
                        const int* __restrict__ oflag,
                        float* __restrict__ out,
                        int C, int H, int W, int nTX) {
    constexpr int WS = TS + 2 * RP;     // source window side
    constexpr int NSRC = WS * WS;
    constexpr float THR = (float)(RP - 1);
    __shared__ float s_num[NCH][TS * TS];
    __shared__ float s_cnt[TS * TS];

    const int b   = blockIdx.z;
    const int c0  = blockIdx.y * NCH;
    const int tx0 = (blockIdx.x % nTX) * TS;
    const int ty0 = (blockIdx.x / nTX) * TS;
    const int t   = threadIdx.x;
    const int HW  = H * W;
    const float* flx = flow + (size_t)b * 2 * HW;
    const float* fly = flx + HW;
    const float* fb  = feat + ((size_t)b * C + c0) * HW;

    for (int i = t; i < TS * TS; i += 256) {
        s_cnt[i] = 0.f;
#pragma unroll
        for (int ch = 0; ch < NCH; ++ch) s_num[ch][i] = 0.f;
    }
    __syncthreads();

    for (int sp = t; sp < NSRC; sp += 256) {
        const int wy = sp / WS, wx = sp - wy * WS;
        const int y = ty0 - RP + wy, x = tx0 - RP + wx;
        if (y < 0 || y >= H || x < 0 || x >= W) continue;
        const float dx = flx[(size_t)y * W + x];
        const float dy = fly[(size_t)y * W + x];
        if (fabsf(dx) > THR || fabsf(dy) > THR) continue;  // outlier pre-pass
        const float fx = dx + (float)x, fy = dy + (float)y;
        const float x0f = floorf(fx), y0f = floorf(fy);
        const int x0 = (int)x0f, y0 = (int)y0f;
        const float ax = fx - x0f, ay = fy - y0f;
        const float w00 = (1.f - ax) * (1.f - ay);
        const float w10 = ax * (1.f - ay);
        const float w01 = (1.f - ax) * ay;
        const float w11 = ax * ay;
        // interior ownership (interior cells are in-image by construction)
        const int lx0 = x0 - tx0, ly0 = y0 - ty0;
        const bool inx0 = (lx0 >= 0) & (lx0 < TS);
        const bool inx1 = (lx0 + 1 >= 0) & (lx0 + 1 < TS);
        const bool iny0 = (ly0 >= 0) & (ly0 < TS);
        const bool iny1 = (ly0 + 1 >= 0) & (ly0 + 1 < TS);
        const bool in00 = inx0 & iny0, in10 = inx1 & iny0;
        const bool in01 = inx0 & iny1, in11 = inx1 & iny1;
        if (!(in00 | in10 | in01 | in11)) continue;

        float f[NCH];
        const float* fp = fb + (size_t)y * W + x;
#pragma unroll
        for (int ch = 0; ch < NCH; ++ch) f[ch] = fp[(size_t)ch * HW];

        const int cell = ly0 * TS + lx0;
        if (in00) {
            lds_fadd(&s_cnt[cell], w00);
#pragma unroll
            for (int ch = 0; ch < NCH; ++ch)
                lds_fadd(&s_num[ch][cell], f[ch] * w00);
        }
        if (in10) {
            lds_fadd(&s_cnt[cell + 1], w10);
#pragma unroll
            for (int ch = 0; ch < NCH; ++ch)
                lds_fadd(&s_num[ch][cell + 1], f[ch] * w10);
        }
        if (in01) {
            lds_fadd(&s_cnt[cell + TS], w01);
#pragma unroll
            for (int ch = 0; ch < NCH; ++ch)
                lds_fadd(&s_num[ch][cell + TS], f[ch] * w01);
        }
        if (in11) {
            lds_fadd(&s_cnt[cell + TS + 1], w11);
#pragma unroll
            for (int ch = 0; ch < NCH; ++ch)
                lds_fadd(&s_num[ch][cell + TS + 1], f[ch] * w11);
        }
    }
    // Drain the untracked asm DS ops before the barrier/epilogue reads.
    asm volatile("s_waitcnt lgkmcnt(0)" ::: "memory");
    __syncthreads();

    const int has = *oflag;   // uniform: overlay only if outliers existed
    for (int i = t; i < TS * TS; i += 256) {
        const int ly = i / TS, lx = i - ly * TS;
        const size_t px = (size_t)(ty0 + ly) * W + (tx0 + lx);
        float cv = s_cnt[i];
        if (has) cv += cnt_ov[(size_t)b * HW + px];
        const float denom = (cv == 0.f) ? 1.f : cv;
        const float inv = 1.f / denom;
#pragma unroll
        for (int ch = 0; ch < NCH; ++ch) {
            float v = s_num[ch][i];
            const size_t go = ((size_t)b * C + c0 + ch) * HW + px;
            if (has) v += out[go];
            out[go] = v * inv;
        }
    }
}

extern "C" void kernel_launch(void* const* d_in, const int* in_sizes, int n_in,
                              void* d_out, int out_size, void* d_ws, size_t ws_size,
                              hipStream_t stream) {
    (void)in_sizes; (void)n_in; (void)ws_size;

    const float* img  = (const float*)d_in[0];
    const float* flow = (const float*)d_in[1];
    const float* P[4][6];
    for (int i = 0; i < 4; ++i)
        for (int j = 0; j < 6; ++j)
            P[i][j] = (const float*)d_in[2 + 6 * i + j];

    const int Bn = 16;
    float* ws = (float*)d_ws;
    float* bufA = ws;                       // 16M floats
    float* bufB = ws + 16777216;            // 16M floats
    float* flA  = ws + 33554432;            // 2M floats
    float* flB  = ws + 35651584;            // 512K floats
    float* cnt  = ws + 36175872;            // 1M floats (outlier cnt overlay)
    int*   flag = (int*)(ws + 37224448);    // outlier-present flag
    float* out  = (float*)d_out;

    hipMemsetAsync(d_out, 0, (size_t)out_size * sizeof(float), stream);

    auto conv = [&](const float* in, const float* w, const float* b,
                    const float* a, float* o, int Ci, int Hi, int Wi,
                    int Co, int stride) {
        const int Ho = Hi / stride, Wo = Wi / stride;
        const int TS = (Wo >= 128) ? 32 : 16;
        const int nTX = Wo / TS, nTY = Ho / TS;
        dim3 grid(nTX * nTY, Co / 8, Bn);
        if (stride == 1) {
            if (TS == 32)
                hipLaunchKernelGGL((conv3x3_tile_kernel<1, 32>), grid, dim3(256), 0,
                                   stream, in, w, b, a, o, Ci, Hi, Wi, Co, Ho, Wo, nTX);
            else
                hipLaunchKernelGGL((conv3x3_tile_kernel<1, 16>), grid, dim3(256), 0,
                                   stream, in, w, b, a, o, Ci, Hi, Wi, Co, Ho, Wo, nTX);
        } else {
            if (TS == 32)
                hipLaunchKernelGGL((conv3x3_tile_kernel<2, 32>), grid, dim3(256), 0,
                                   stream, in, w, b, a, o, Ci, Hi, Wi, Co, Ho, Wo, nTX);
            else
                hipLaunchKernelGGL((conv3x3_tile_kernel<2, 16>), grid, dim3(256), 0,
                                   stream, in, w, b, a, o, Ci, Hi, Wi, Co, Ho, Wo, nTX);
        }
    };
    auto halve = [&](const float* in, float* o, int Hi, int Wi) {
        const int Ho = Hi / 2, Wo = Wi / 2;
        const int total = Bn * 2 * Ho * Wo;
        hipLaunchKernelGGL(halve_flow_kernel, dim3(CDIV(total, 256)), dim3(256),
                           0, stream, in, o, Bn * 2, Ho, Wo, Hi, Wi);
    };

    float* p1 = out;
    float* p2 = p1 + (size_t)Bn * 16 * 256 * 256;
    float* p3 = p2 + (size_t)Bn * 32 * 128 * 128;
    float* p4 = p3 + (size_t)Bn * 64 * 64 * 64;

    // ---- level 1
    conv(img,  P[0][0], P[0][1], P[0][2], bufA, 3, 512, 512, 16, 2);
    conv(bufA, P[0][3], P[0][4], P[0][5], bufB, 16, 256, 256, 16, 1);
    halve(flow, flA, 512, 512);
    {
        const int C = 16, H = 256, W = 256;
        hipMemsetAsync(cnt, 0, (size_t)Bn * H * W * sizeof(float), stream);
        hipMemsetAsync(flag, 0, sizeof(int), stream);
        hipLaunchKernelGGL(splat_outlier_kernel, dim3(CDIV(Bn * H * W, 256)),
                           dim3(256), 0, stream, bufB, flA, p1, cnt, flag,
                           Bn, C, H, W, 7.f);
        hipLaunchKernelGGL((splat_owner_kernel<32, 8, 8>),
                           dim3((W / 32) * (H / 32), C / 8, Bn), dim3(256), 0,
                           stream, bufB, flA, cnt, flag, p1, C, H, W, W / 32);
    }

    // ---- level 2
    conv(bufB, P[1][0], P[1][1], P[1][2], bufA, 16, 256, 256, 32, 2);
    conv(bufA, P[1][3], P[1][4], P[1][5], bufB, 32, 128, 128, 32, 1);
    halve(flA, flB, 256, 256);
    {
        const int C = 32, H = 128, W = 128;
        hipMemsetAsync(cnt, 0, (size_t)Bn * H * W * sizeof(float), stream);
        hipMemsetAsync(flag, 0, sizeof(int), stream);
        hipLaunchKernelGGL(splat_outlier_kernel, dim3(CDIV(Bn * H * W, 256)),
                           dim3(256), 0, stream, bufB, flB, p2, cnt, flag,
                           Bn, C, H, W, 3.f);
        hipLaunchKernelGGL((splat_owner_kernel<32, 4, 8>),
                           dim3((W / 32) * (H / 32), C / 8, Bn), dim3(256), 0,
                           stream, bufB, flB, cnt, flag, p2, C, H, W, W / 32);
    }

    // ---- level 3
    conv(bufB, P[2][0], P[2][1], P[2][2], bufA, 32, 128, 128, 64, 2);
    conv(bufA, P[2][3], P[2][4], P[2][5], bufB, 64, 64, 64, 64, 1);
    halve(flB, flA, 128, 128);
    {
        const int C = 64, H = 64, W = 64;
        hipMemsetAsync(cnt, 0, (size_t)Bn * H * W * sizeof(float), stream);
        hipMemsetAsync(flag, 0, sizeof(int), stream);
        hipLaunchKernelGGL(splat_outlier_kernel, dim3(CDIV(Bn * H * W, 256)),
                           dim3(256), 0, stream, bufB, flA, p3, cnt, flag,
                           Bn, C, H, W, 2.f);
        hipLaunchKernelGGL((splat_owner_kernel<16, 3, 16>),
                           dim3((W / 16) * (H / 16), C / 16, Bn), dim3(256), 0,
                           stream, bufB, flA, cnt, flag, p3, C, H, W, W / 16);
    }

    // ---- level 4
    conv(bufB, P[3][0], P[3][1], P[3][2], bufA, 64, 64, 64, 128, 2);
    conv(bufA, P[3][3], P[3][4], P[3][5], bufB, 128, 32, 32, 128, 1);
    halve(flA, flB, 64, 64);
    {
        const int C = 128, H = 32, W = 32;
        hipMemsetAsync(cnt, 0, (size_t)Bn * H * W * sizeof(float), stream);
        hipMemsetAsync(flag, 0, sizeof(int), stream);
        hipLaunchKernelGGL(splat_outlier_kernel, dim3(CDIV(Bn * H * W, 256)),
                           dim3(256), 0, stream, bufB, flB, p4, cnt, flag,
                           Bn, C, H, W, 1.f);
        hipLaunchKernelGGL((splat_owner_kernel<16, 2, 16>),
                           dim3((W / 16) * (H / 16), C / 16, Bn), dim3(256), 0,
                           stream, bufB, flB, cnt, flag, p4, C, H, W, W / 16);
    }
}

// Round 5
// 1990.156 us; speedup vs baseline: 1.1827x; 1.1785x over previous
//
#include <hip/hip_runtime.h>

#define CDIV(a, b) (((a) + (b) - 1) / (b))

// Native fp32 atomic add for GLOBAL memory (outlier path only; ~never taken).
__device__ __forceinline__ void fadd_native(float* p, float v) {
    unsafeAtomicAdd(p, v);
}

// ---------------------------------------------------------------------------
// Tiled conv 3x3 pad 1 stride {1,2} + bias + PReLU.
// ---------------------------------------------------------------------------
template <int STRIDE, int TS>
__global__ __launch_bounds__(256)
void conv3x3_tile_kernel(const float* __restrict__ in,
                         const float* __restrict__ wgt,
                         const float* __restrict__ bias,
                         const float* __restrict__ alpha,
                         float* __restrict__ out,
                         int Ci, int Hi, int Wi, int Co, int Ho, int Wo,
                         int nTX) {
    constexpr int PB = TS / 16;               // pixels per thread per dim
    constexpr int IS = TS * STRIDE + 2;       // input tile side
    constexpr int KO = 8;
    constexpr int SP = (PB - 1) * STRIDE + 3; // per-thread tap span
    __shared__ float s_in[IS * IS];
    __shared__ float s_w[KO * 12];

    const int b   = blockIdx.z;
    const int co0 = blockIdx.y * KO;
    const int tX  = (blockIdx.x % nTX) * TS;
    const int tY  = (blockIdx.x / nTX) * TS;
    const int t   = threadIdx.x;
    const int tcx = t & 15, tcy = t >> 4;
    const int ox0 = PB * tcx, oy0 = PB * tcy;

    float acc[KO][PB][PB];
#pragma unroll
    for (int ko = 0; ko < KO; ++ko)
#pragma unroll
        for (int dy = 0; dy < PB; ++dy)
#pragma unroll
            for (int dx = 0; dx < PB; ++dx) acc[ko][dy][dx] = 0.f;

    const float* inb = in + (size_t)b * Ci * Hi * Wi;
    const int ix0 = tX * STRIDE - 1, iy0 = tY * STRIDE - 1;

    for (int ci = 0; ci < Ci; ++ci) {
        __syncthreads();
        const float* inp = inb + (size_t)ci * Hi * Wi;
        for (int i = t; i < IS * IS; i += 256) {
            const int r = i / IS, c = i - r * IS;
            const int gy = iy0 + r, gx = ix0 + c;
            float v = 0.f;
            if (gy >= 0 && gy < Hi && gx >= 0 && gx < Wi)
                v = inp[(size_t)gy * Wi + gx];
            s_in[i] = v;
        }
        if (t < KO * 9) {
            const int ko = t / 9, k = t - ko * 9;
            s_w[ko * 12 + k] = wgt[((size_t)(co0 + ko) * Ci + ci) * 9 + k];
        }
        __syncthreads();

        float tap[SP][SP];
#pragma unroll
        for (int r = 0; r < SP; ++r)
#pragma unroll
            for (int c = 0; c < SP; ++c)
                tap[r][c] = s_in[(oy0 * STRIDE + r) * IS + ox0 * STRIDE + c];

#pragma unroll
        for (int ko = 0; ko < KO; ++ko) {
            float w[9];
#pragma unroll
            for (int k = 0; k < 9; ++k) w[k] = s_w[ko * 12 + k];
#pragma unroll
            for (int dy = 0; dy < PB; ++dy)
#pragma unroll
                for (int dx = 0; dx < PB; ++dx) {
                    float a = acc[ko][dy][dx];
#pragma unroll
                    for (int ky = 0; ky < 3; ++ky)
#pragma unroll
                        for (int kx = 0; kx < 3; ++kx)
                            a += tap[dy * STRIDE + ky][dx * STRIDE + kx] *
                                 w[ky * 3 + kx];
                    acc[ko][dy][dx] = a;
                }
        }
    }

#pragma unroll
    for (int ko = 0; ko < KO; ++ko) {
        const int co = co0 + ko;
        const float bv = bias[co], av = alpha[co];
#pragma unroll
        for (int dy = 0; dy < PB; ++dy) {
            const int oy = tY + oy0 + dy;
#pragma unroll
            for (int dx = 0; dx < PB; ++dx) {
                const int ox = tX + ox0 + dx;
                float v = acc[ko][dy][dx] + bv;
                v = v >= 0.f ? v : av * v;
                out[(((size_t)b * Co + co) * Ho + oy) * Wo + ox] = v;
            }
        }
    }
}

// ---------------------------------------------------------------------------
// flow halving: 2x2 mean * 0.5 == sum * 0.125
// ---------------------------------------------------------------------------
__global__ void halve_flow_kernel(const float* __restrict__ in,
                                  float* __restrict__ out,
                                  int BC, int Ho, int Wo, int Hi, int Wi) {
    const int idx = blockIdx.x * blockDim.x + threadIdx.x;
    const int total = BC * Ho * Wo;
    if (idx >= total) return;
    const int wo = idx % Wo;
    int t = idx / Wo;
    const int ho = t % Ho;
    const int bc = t / Ho;
    const float* p = in + ((size_t)bc * Hi + 2 * ho) * Wi + 2 * wo;
    out[idx] = (p[0] + p[1] + p[Wi] + p[Wi + 1]) * 0.125f;
}

// ---------------------------------------------------------------------------
// Outlier splat pre-pass: sources with |flow| > thr go through device atomics
// into the num/cnt overlay. Sets *flag so the gather kernel adds the overlay.
// thr MUST equal (float)(K-1) of the matching gather kernel.
// ---------------------------------------------------------------------------
__global__ void splat_outlier_kernel(const float* __restrict__ feat,
                                     const float* __restrict__ flow,
                                     float* __restrict__ num,
                                     float* __restrict__ cnt,
                                     int* __restrict__ flag,
                                     int B, int C, int H, int W, float thr) {
    const int HW = H * W;
    const int idx = blockIdx.x * blockDim.x + threadIdx.x;
    if (idx >= B * HW) return;
    const int b = idx / HW, px = idx - b * HW;
    const int y = px / W, x = px - y * W;
    const float dx = flow[(size_t)b * 2 * HW + px];
    const float dy = flow[(size_t)b * 2 * HW + HW + px];
    if (fabsf(dx) <= thr && fabsf(dy) <= thr) return;   // fast-path source
    atomicAdd(flag, 1);
    const float fx = dx + (float)x, fy = dy + (float)y;
    const float x0f = floorf(fx), y0f = floorf(fy);
    const int x0 = (int)x0f, y0 = (int)y0f;
    const float ax = fx - x0f, ay = fy - y0f;
    const float w[4] = {(1.f - ax) * (1.f - ay), ax * (1.f - ay),
                        (1.f - ax) * ay,         ax * ay};
    const int cx[4] = {x0, x0 + 1, x0, x0 + 1};
    const int cy[4] = {y0, y0, y0 + 1, y0 + 1};
    float* cb = cnt + (size_t)b * HW;
    for (int k = 0; k < 4; ++k) {
        if (cx[k] < 0 || cx[k] >= W || cy[k] < 0 || cy[k] >= H) continue;
        if (w[k] == 0.f) continue;
        const size_t d = (size_t)cy[k] * W + cx[k];
        fadd_native(cb + d, w[k]);
        for (int c = 0; c < C; ++c)
            fadd_native(num + ((size_t)b * C + c) * HW + d,
                        feat[((size_t)b * C + c) * HW + px] * w[k]);
    }
}

// ---------------------------------------------------------------------------
// GATHER splat: zero atomics. Each thread owns a RUN-wide horizontal strip of
// dest pixels and accumulates num/cnt in REGISTERS.
//  - stage tile-relative target coords (fx,fy) of the source window in LDS
//    (outliers & out-of-image staged as 1e9 -> fail all hit tests; handled
//    exactly by splat_outlier_kernel)
//  - phase 1: scan (2K+1)x(RUN+2K) candidates, compact hit indices into a
//    per-thread LDS list (plain conditional writes)
//  - phase 2: dense walk of own hits: weights + NCH feature gathers + FMA
//  - epilogue: divide, plain float4 stores
// Coverage: |flow| <= K-1 componentwise => both bilinear corners of a source
// lie within +-K of it, so the window/scan ranges are exact.
// ---------------------------------------------------------------------------
template <int TS, int K, int NCH, int HCAP>
__global__ __launch_bounds__(256)
void splat_gather_kernel(const float* __restrict__ feat,
                         const float* __restrict__ flow,
                         const float* __restrict__ cnt_ov,
                         const int* __restrict__ oflag,
                         float* __restrict__ out,
                         int C, int H, int W, int nTX) {
    constexpr int WS   = TS + 2 * K;   // source window side
    constexpr int SSTR = WS + 1;       // padded LDS stride (odd -> bank spread)
    constexpr int RUN  = TS * TS / 256;  // dest pixels per thread (4 or 1)
    constexpr int TPR  = TS / RUN;       // threads per dest row
    constexpr float THR = (float)(K - 1);
    __shared__ float s_fx[WS * SSTR];
    __shared__ float s_fy[WS * SSTR];
    __shared__ unsigned short s_hit[256 * HCAP];

    const int b   = blockIdx.z;
    const int c0  = blockIdx.y * NCH;
    const int tx0 = (blockIdx.x % nTX) * TS;
    const int ty0 = (blockIdx.x / nTX) * TS;
    const int t   = threadIdx.x;
    const int HW  = H * W;
    const float* flx = flow + (size_t)b * 2 * HW;
    const float* fly = flx + HW;
    const float* fb  = feat + ((size_t)b * C + c0) * HW;

    // ---- stage tile-relative target coords
    for (int i = t; i < WS * WS; i += 256) {
        const int wsy = i / WS, wsx = i - wsy * WS;
        const int gy = ty0 - K + wsy, gx = tx0 - K + wsx;
        float fxr = 1e9f, fyr = 1e9f;
        if (gy >= 0 && gy < H && gx >= 0 && gx < W) {
            const float dxf = flx[(size_t)gy * W + gx];
            const float dyf = fly[(size_t)gy * W + gx];
            if (fabsf(dxf) <= THR && fabsf(dyf) <= THR) {
                fxr = dxf + (float)(gx - tx0);
                fyr = dyf + (float)(gy - ty0);
            }
        }
        s_fx[wsy * SSTR + wsx] = fxr;
        s_fy[wsy * SSTR + wsx] = fyr;
    }
    __syncthreads();

    const int r  = t / TPR;            // owned dest row (tile-relative)
    const int x0 = (t % TPR) * RUN;    // owned dest col start

    // ---- phase 1: scan candidates, compact hits
    int n = 0;
    unsigned short* hl = s_hit + t * HCAP;
#pragma unroll
    for (int dy = 0; dy <= 2 * K; ++dy) {
        const int wsy = r + dy;
        const int base = wsy * SSTR + x0;
#pragma unroll
        for (int dxx = 0; dxx < RUN + 2 * K; ++dxx) {
            const float fyr = s_fy[base + dxx];
            const float fxr = s_fx[base + dxx];
            const float ty = fyr - (float)r;
            const float ux = fxr - (float)x0;
            if (ty > -1.f && ty < 1.f && ux > -1.f && ux < (float)RUN &&
                n < HCAP) {
                hl[n] = (unsigned short)((wsy << 6) | (x0 + dxx));
                ++n;
            }
        }
    }

    // ---- phase 2: dense accumulate into registers
    float acc[RUN][NCH];
    float cnt[RUN];
#pragma unroll
    for (int m = 0; m < RUN; ++m) {
        cnt[m] = 0.f;
#pragma unroll
        for (int ch = 0; ch < NCH; ++ch) acc[m][ch] = 0.f;
    }

    for (int k = 0; k < n; ++k) {
        const int idx = hl[k];
        const int wsy = idx >> 6, wsx = idx & 63;
        const float fxr = s_fx[wsy * SSTR + wsx];
        const float fyr = s_fy[wsy * SSTR + wsx];
        const float wy = 1.f - fabsf(fyr - (float)r);   // > 0 by construction
        const float ux = fxr - (float)x0;
        const int gsy = ty0 - K + wsy, gsx = tx0 - K + wsx;
        const float* fp = fb + (size_t)gsy * W + gsx;
        float wm[RUN];
#pragma unroll
        for (int m = 0; m < RUN; ++m) {
            wm[m] = fmaxf(0.f, 1.f - fabsf(ux - (float)m)) * wy;
            cnt[m] += wm[m];
        }
#pragma unroll
        for (int ch = 0; ch < NCH; ++ch) {
            const float f = fp[(size_t)ch * HW];
#pragma unroll
            for (int m = 0; m < RUN; ++m)
                acc[m][ch] = fmaf(wm[m], f, acc[m][ch]);
        }
    }

    // ---- epilogue: divide + plain stores (overlay only if outliers existed)
    const int has = *oflag;
    const int gy = ty0 + r;
    const size_t rowoff = (size_t)gy * W + (tx0 + x0);
    float inv[RUN];
#pragma unroll
    for (int m = 0; m < RUN; ++m) {
        float cv = cnt[m];
        if (has) cv += cnt_ov[(size_t)b * HW + rowoff + m];
        inv[m] = 1.f / ((cv == 0.f) ? 1.f : cv);
    }
#pragma unroll
    for (int ch = 0; ch < NCH; ++ch) {
        const size_t go = ((size_t)b * C + (c0 + ch)) * HW + rowoff;
        if constexpr (RUN == 4) {
            float vv[4];
#pragma unroll
            for (int m = 0; m < 4; ++m) {
                float x = acc[m][ch];
                if (has) x += out[go + m];
                vv[m] = x * inv[m];
            }
            float4 v4 = {vv[0], vv[1], vv[2], vv[3]};
            *reinterpret_cast<float4*>(out + go) = v4;
        } else {
            float x = acc[0][ch];
            if (has) x += out[go];
            out[go] = x * inv[0];
        }
    }
}

extern "C" void kernel_launch(void* const* d_in, const int* in_sizes, int n_in,
                              void* d_out, int out_size, void* d_ws, size_t ws_size,
                              hipStream_t stream) {
    (void)in_sizes; (void)n_in; (void)ws_size;

    const float* img  = (const float*)d_in[0];
    const float* flow = (const float*)d_in[1];
    const float* P[4][6];
    for (int i = 0; i < 4; ++i)
        for (int j = 0; j < 6; ++j)
            P[i][j] = (const float*)d_in[2 + 6 * i + j];

    const int Bn = 16;
    float* ws = (float*)d_ws;
    float* bufA = ws;                       // 16M floats
    float* bufB = ws + 16777216;            // 16M floats
    float* flA  = ws + 33554432;            // 2M floats
    float* flB  = ws + 35651584;            // 512K floats
    float* cnt  = ws + 36175872;            // 1M floats (outlier cnt overlay)
    int*   flag = (int*)(ws + 37224448);    // outlier-present flag
    float* out  = (float*)d_out;

    hipMemsetAsync(d_out, 0, (size_t)out_size * sizeof(float), stream);

    auto conv = [&](const float* in, const float* w, const float* b,
                    const float* a, float* o, int Ci, int Hi, int Wi,
                    int Co, int stride) {
        const int Ho = Hi / stride, Wo = Wi / stride;
        const int TS = (Wo >= 128) ? 32 : 16;
        const int nTX = Wo / TS, nTY = Ho / TS;
        dim3 grid(nTX * nTY, Co / 8, Bn);
        if (stride == 1) {
            if (TS == 32)
                hipLaunchKernelGGL((conv3x3_tile_kernel<1, 32>), grid, dim3(256), 0,
                                   stream, in, w, b, a, o, Ci, Hi, Wi, Co, Ho, Wo, nTX);
            else
                hipLaunchKernelGGL((conv3x3_tile_kernel<1, 16>), grid, dim3(256), 0,
                                   stream, in, w, b, a, o, Ci, Hi, Wi, Co, Ho, Wo, nTX);
        } else {
            if (TS == 32)
                hipLaunchKernelGGL((conv3x3_tile_kernel<2, 32>), grid, dim3(256), 0,
                                   stream, in, w, b, a, o, Ci, Hi, Wi, Co, Ho, Wo, nTX);
            else
                hipLaunchKernelGGL((conv3x3_tile_kernel<2, 16>), grid, dim3(256), 0,
                                   stream, in, w, b, a, o, Ci, Hi, Wi, Co, Ho, Wo, nTX);
        }
    };
    auto halve = [&](const float* in, float* o, int Hi, int Wi) {
        const int Ho = Hi / 2, Wo = Wi / 2;
        const int total = Bn * 2 * Ho * Wo;
        hipLaunchKernelGGL(halve_flow_kernel, dim3(CDIV(total, 256)), dim3(256),
                           0, stream, in, o, Bn * 2, Ho, Wo, Hi, Wi);
    };

    float* p1 = out;
    float* p2 = p1 + (size_t)Bn * 16 * 256 * 256;
    float* p3 = p2 + (size_t)Bn * 32 * 128 * 128;
    float* p4 = p3 + (size_t)Bn * 64 * 64 * 64;

    // ---- level 1 (flow sigma = 1, THR=3 -> K=4)
    conv(img,  P[0][0], P[0][1], P[0][2], bufA, 3, 512, 512, 16, 2);
    conv(bufA, P[0][3], P[0][4], P[0][5], bufB, 16, 256, 256, 16, 1);
    halve(flow, flA, 512, 512);
    {
        const int C = 16, H = 256, W = 256;
        hipMemsetAsync(cnt, 0, (size_t)Bn * H * W * sizeof(float), stream);
        hipMemsetAsync(flag, 0, sizeof(int), stream);
        hipLaunchKernelGGL(splat_outlier_kernel, dim3(CDIV(Bn * H * W, 256)),
                           dim3(256), 0, stream, bufB, flA, p1, cnt, flag,
                           Bn, C, H, W, 3.f);
        hipLaunchKernelGGL((splat_gather_kernel<32, 4, 16, 40>),
                           dim3((W / 32) * (H / 32), C / 16, Bn), dim3(256), 0,
                           stream, bufB, flA, cnt, flag, p1, C, H, W, W / 32);
    }

    // ---- level 2 (flow sigma = 0.25, THR=2 -> K=3)
    conv(bufB, P[1][0], P[1][1], P[1][2], bufA, 16, 256, 256, 32, 2);
    conv(bufA, P[1][3], P[1][4], P[1][5], bufB, 32, 128, 128, 32, 1);
    halve(flA, flB, 256, 256);
    {
        const int C = 32, H = 128, W = 128;
        hipMemsetAsync(cnt, 0, (size_t)Bn * H * W * sizeof(float), stream);
        hipMemsetAsync(flag, 0, sizeof(int), stream);
        hipLaunchKernelGGL(splat_outlier_kernel, dim3(CDIV(Bn * H * W, 256)),
                           dim3(256), 0, stream, bufB, flB, p2, cnt, flag,
                           Bn, C, H, W, 2.f);
        hipLaunchKernelGGL((splat_gather_kernel<32, 3, 16, 40>),
                           dim3((W / 32) * (H / 32), C / 16, Bn), dim3(256), 0,
                           stream, bufB, flB, cnt, flag, p2, C, H, W, W / 32);
    }

    // ---- level 3 (flow sigma = 0.0625, THR=1 -> K=2)
    conv(bufB, P[2][0], P[2][1], P[2][2], bufA, 32, 128, 128, 64, 2);
    conv(bufA, P[2][3], P[2][4], P[2][5], bufB, 64, 64, 64, 64, 1);
    halve(flB, flA, 128, 128);
    {
        const int C = 64, H = 64, W = 64;
        hipMemsetAsync(cnt, 0, (size_t)Bn * H * W * sizeof(float), stream);
        hipMemsetAsync(flag, 0, sizeof(int), stream);
        hipLaunchKernelGGL(splat_outlier_kernel, dim3(CDIV(Bn * H * W, 256)),
                           dim3(256), 0, stream, bufB, flA, p3, cnt, flag,
                           Bn, C, H, W, 1.f);
        hipLaunchKernelGGL((splat_gather_kernel<16, 2, 16, 24>),
                           dim3((W / 16) * (H / 16), C / 16, Bn), dim3(256), 0,
                           stream, bufB, flA, cnt, flag, p3, C, H, W, W / 16);
    }

    // ---- level 4 (flow sigma = 0.016, THR=1 -> K=2)
    conv(bufB, P[3][0], P[3][1], P[3][2], bufA, 64, 64, 64, 128, 2);
    conv(bufA, P[3][3], P[3][4], P[3][5], bufB, 128, 32, 32, 128, 1);
    halve(flA, flB, 64, 64);
    {
        const int C = 128, H = 32, W = 32;
        hipMemsetAsync(cnt, 0, (size_t)Bn * H * W * sizeof(float), stream);
        hipMemsetAsync(flag, 0, sizeof(int), stream);
        hipLaunchKernelGGL(splat_outlier_kernel, dim3(CDIV(Bn * H * W, 256)),
                           dim3(256), 0, stream, bufB, flB, p4, cnt, flag,
                           Bn, C, H, W, 1.f);
        hipLaunchKernelGGL((splat_gather_kernel<16, 2, 16, 24>),
                           dim3((W / 16) * (H / 16), C / 16, Bn), dim3(256), 0,
                           stream, bufB, flB, cnt, flag, p4, C, H, W, W / 16);
    }
}

// Round 6
// 1173.102 us; speedup vs baseline: 2.0064x; 1.6965x over previous
//
#include <hip/hip_runtime.h>

#define CDIV(a, b) (((a) + (b) - 1) / (b))

typedef float __attribute__((ext_vector_type(2))) f32x2;
typedef float __attribute__((ext_vector_type(4))) f32x4;

// Packed fp32 FMA: d = a*b + d (per 32-bit half). MI355X full fp32 rate
// (157 TF) is only reachable via VOP3P packed math; scalar v_fmac = half.
__device__ __forceinline__ void pk_fma(f32x2& d, f32x2 a, f32x2 b) {
    asm("v_pk_fma_f32 %0, %1, %2, %0" : "+v"(d) : "v"(a), "v"(b));
}

// Native fp32 atomic add for GLOBAL memory (outlier path only; ~never taken).
__device__ __forceinline__ void fadd_native(float* p, float v) {
    unsafeAtomicAdd(p, v);
}

// ---------------------------------------------------------------------------
// Conv 3x3 pad1 stride{1,2} + bias + PReLU, packed-channel version.
// 256 threads as 16x16; thread computes PX x PY pixels (PX=TW/16, PY=TH/16)
// for 16 output channels held as 8 channel-pair f32x2 accumulators.
// Register double-buffered staging: plane ci+CB is loaded to regs while
// computing plane ci from LDS. Weights staged transposed [k][ko] so 4
// channels come from one broadcast ds_read_b128.
// ---------------------------------------------------------------------------
template <int STRIDE, int TW, int TH, int CB>
__global__ __launch_bounds__(256)
void conv3x3_pk_kernel(const float* __restrict__ in,
                       const float* __restrict__ wgt,
                       const float* __restrict__ bias,
                       const float* __restrict__ alpha,
                       float* __restrict__ out,
                       int Ci, int Hi, int Wi, int Co, int Ho, int Wo,
                       int nTX) {
    constexpr int KO  = 16;
    constexpr int PX  = TW / 16, PY = TH / 16;
    constexpr int ISX = TW * STRIDE + 2;
    constexpr int ISY = TH * STRIDE + 2;
    constexpr int ISS = ISX * ISY;
    constexpr int NST = (CB * ISS + 255) / 256;       // staging regs/thread
    constexpr int NWT = (CB * 9 * KO + 255) / 256;    // weight regs/thread
    __shared__ float s_in[CB * ISS];
    __shared__ __align__(16) float s_wt[CB * 9 * KO]; // [p][k][ko]

    const int b   = blockIdx.z;
    const int co0 = blockIdx.y * KO;
    const int tX  = (blockIdx.x % nTX) * TW;
    const int tY  = (blockIdx.x / nTX) * TH;
    const int t   = threadIdx.x;
    const int tcx = t & 15, tcy = t >> 4;
    const int ox0 = PX * tcx, oy0 = PY * tcy;
    const int HiWi = Hi * Wi;

    // ---- precompute staging offsets + validity (ci-independent)
    int  poff[NST];
    bool pval[NST];
    const int ix0 = tX * STRIDE - 1, iy0 = tY * STRIDE - 1;
#pragma unroll
    for (int s = 0; s < NST; ++s) {
        const int i = t + s * 256;
        int off = 0; bool v = false;
        if (i < CB * ISS) {
            const int p = i / ISS, j = i - p * ISS;
            const int r = j / ISX, c = j - r * ISX;
            const int gy = iy0 + r, gx = ix0 + c;
            v = (gy >= 0) && (gy < Hi) && (gx >= 0) && (gx < Wi);
            off = v ? (p * HiWi + gy * Wi + gx) : 0;
        }
        poff[s] = off; pval[s] = v;
    }
    // ---- precompute weight slots
    int  wofs[NWT], wdst[NWT];
    bool wvs[NWT];
#pragma unroll
    for (int s = 0; s < NWT; ++s) {
        const int j = t + s * 256;
        bool v = j < CB * 9 * KO;
        int ofs = 0, dst = 0;
        if (v) {
            const int p = j / (9 * KO), rem = j - p * 9 * KO;
            const int k = rem / KO, ko = rem - k * KO;
            ofs = ((co0 + ko) * Ci + p) * 9 + k;   // + ci*9 at load time
            dst = (p * 9 + k) * KO + ko;
        }
        wofs[s] = ofs; wdst[s] = dst; wvs[s] = v;
    }

    f32x2 acc2[KO / 2][PY][PX];
#pragma unroll
    for (int cp = 0; cp < KO / 2; ++cp)
#pragma unroll
        for (int dy = 0; dy < PY; ++dy)
#pragma unroll
            for (int dx = 0; dx < PX; ++dx) acc2[cp][dy][dx] = (f32x2){0.f, 0.f};

    const float* inb = in + (size_t)b * Ci * HiWi;

    // ---- prologue: load ci=0 block into regs
    float rs[NST], rw[NWT];
#pragma unroll
    for (int s = 0; s < NST; ++s) rs[s] = pval[s] ? inb[poff[s]] : 0.f;
#pragma unroll
    for (int s = 0; s < NWT; ++s) rw[s] = wvs[s] ? wgt[wofs[s]] : 0.f;

    const int bx = ox0 * STRIDE, by = oy0 * STRIDE;

    for (int ci = 0; ci < Ci; ci += CB) {
        __syncthreads();   // previous compute finished reading LDS
#pragma unroll
        for (int s = 0; s < NST; ++s) {
            const int i = t + s * 256;
            if (i < CB * ISS) s_in[i] = rs[s];
        }
#pragma unroll
        for (int s = 0; s < NWT; ++s)
            if (wvs[s]) s_wt[wdst[s]] = rw[s];
        // prefetch next block while computing this one
        if (ci + CB < Ci) {
            const float* nb = inb + (size_t)(ci + CB) * HiWi;
            const int w9 = (ci + CB) * 9;
#pragma unroll
            for (int s = 0; s < NST; ++s) rs[s] = pval[s] ? nb[poff[s]] : 0.f;
#pragma unroll
            for (int s = 0; s < NWT; ++s)
                rw[s] = wvs[s] ? wgt[wofs[s] + w9] : 0.f;
        }
        __syncthreads();

#pragma unroll
        for (int p = 0; p < CB; ++p) {
            const float* sp = s_in + p * ISS;
#pragma unroll
            for (int ky = 0; ky < 3; ++ky)
#pragma unroll
                for (int kx = 0; kx < 3; ++kx) {
                    const int k = ky * 3 + kx;
                    f32x2 t2[PY][PX];
#pragma unroll
                    for (int dy = 0; dy < PY; ++dy)
#pragma unroll
                        for (int dx = 0; dx < PX; ++dx) {
                            const float tv =
                                sp[(by + dy * STRIDE + ky) * ISX + bx +
                                   dx * STRIDE + kx];
                            t2[dy][dx] = (f32x2){tv, tv};
                        }
                    const float* wb = s_wt + (p * 9 + k) * KO;
#pragma unroll
                    for (int kq = 0; kq < KO / 4; ++kq) {
                        const f32x4 w4 =
                            *reinterpret_cast<const f32x4*>(wb + 4 * kq);
                        const f32x2 wlo = {w4[0], w4[1]};
                        const f32x2 whi = {w4[2], w4[3]};
#pragma unroll
                        for (int dy = 0; dy < PY; ++dy)
#pragma unroll
                            for (int dx = 0; dx < PX; ++dx) {
                                pk_fma(acc2[2 * kq][dy][dx], t2[dy][dx], wlo);
                                pk_fma(acc2[2 * kq + 1][dy][dx], t2[dy][dx], whi);
                            }
                    }
                }
        }
    }

    // ---- epilogue: bias + PReLU + store
#pragma unroll
    for (int cp = 0; cp < KO / 2; ++cp)
#pragma unroll
        for (int h = 0; h < 2; ++h) {
            const int co = co0 + 2 * cp + h;
            const float bv = bias[co], av = alpha[co];
#pragma unroll
            for (int dy = 0; dy < PY; ++dy) {
                const int oy = tY + oy0 + dy;
#pragma unroll
                for (int dx = 0; dx < PX; ++dx) {
                    const int ox = tX + ox0 + dx;
                    float v = acc2[cp][dy][dx][h] + bv;
                    v = v >= 0.f ? v : av * v;
                    out[(((size_t)b * Co + co) * Ho + oy) * Wo + ox] = v;
                }
            }
        }
}

// ---------------------------------------------------------------------------
// flow halving: 2x2 mean * 0.5 == sum * 0.125
// ---------------------------------------------------------------------------
__global__ void halve_flow_kernel(const float* __restrict__ in,
                                  float* __restrict__ out,
                                  int BC, int Ho, int Wo, int Hi, int Wi) {
    const int idx = blockIdx.x * blockDim.x + threadIdx.x;
    const int total = BC * Ho * Wo;
    if (idx >= total) return;
    const int wo = idx % Wo;
    int t = idx / Wo;
    const int ho = t % Ho;
    const int bc = t / Ho;
    const float* p = in + ((size_t)bc * Hi + 2 * ho) * Wi + 2 * wo;
    out[idx] = (p[0] + p[1] + p[Wi] + p[Wi + 1]) * 0.125f;
}

// ---------------------------------------------------------------------------
// Outlier splat pre-pass: sources with |flow| > thr go through device atomics
// into the num/cnt overlay. Sets *flag so the gather kernel adds the overlay.
// thr MUST equal (float)(K-1) of the matching gather kernel.
// ---------------------------------------------------------------------------
__global__ void splat_outlier_kernel(const float* __restrict__ feat,
                                     const float* __restrict__ flow,
                                     float* __restrict__ num,
                                     float* __restrict__ cnt,
                                     int* __restrict__ flag,
                                     int B, int C, int H, int W, float thr) {
    const int HW = H * W;
    const int idx = blockIdx.x * blockDim.x + threadIdx.x;
    if (idx >= B * HW) return;
    const int b = idx / HW, px = idx - b * HW;
    const int y = px / W, x = px - y * W;
    const float dx = flow[(size_t)b * 2 * HW + px];
    const float dy = flow[(size_t)b * 2 * HW + HW + px];
    if (fabsf(dx) <= thr && fabsf(dy) <= thr) return;   // fast-path source
    atomicAdd(flag, 1);
    const float fx = dx + (float)x, fy = dy + (float)y;
    const float x0f = floorf(fx), y0f = floorf(fy);
    const int x0 = (int)x0f, y0 = (int)y0f;
    const float ax = fx - x0f, ay = fy - y0f;
    const float w[4] = {(1.f - ax) * (1.f - ay), ax * (1.f - ay),
                        (1.f - ax) * ay,         ax * ay};
    const int cx[4] = {x0, x0 + 1, x0, x0 + 1};
    const int cy[4] = {y0, y0, y0 + 1, y0 + 1};
    float* cb = cnt + (size_t)b * HW;
    for (int k = 0; k < 4; ++k) {
        if (cx[k] < 0 || cx[k] >= W || cy[k] < 0 || cy[k] >= H) continue;
        if (w[k] == 0.f) continue;
        const size_t d = (size_t)cy[k] * W + cx[k];
        fadd_native(cb + d, w[k]);
        for (int c = 0; c < C; ++c)
            fadd_native(num + ((size_t)b * C + c) * HW + d,
                        feat[((size_t)b * C + c) * HW + px] * w[k]);
    }
}

// ---------------------------------------------------------------------------
// GATHER splat: zero atomics. Each thread owns a RUN-wide horizontal strip of
// dest pixels and accumulates num/cnt in REGISTERS. (See Round-5 notes.)
// ---------------------------------------------------------------------------
template <int TS, int K, int NCH, int HCAP>
__global__ __launch_bounds__(256)
void splat_gather_kernel(const float* __restrict__ feat,
                         const float* __restrict__ flow,
                         const float* __restrict__ cnt_ov,
                         const int* __restrict__ oflag,
                         float* __restrict__ out,
                         int C, int H, int W, int nTX) {
    constexpr int WS   = TS + 2 * K;   // source window side
    constexpr int SSTR = WS + 1;       // padded LDS stride
    constexpr int RUN  = TS * TS / 256;  // dest pixels per thread (4 or 1)
    constexpr int TPR  = TS / RUN;       // threads per dest row
    constexpr float THR = (float)(K - 1);
    __shared__ float s_fx[WS * SSTR];
    __shared__ float s_fy[WS * SSTR];
    __shared__ unsigned short s_hit[256 * HCAP];

    const int b   = blockIdx.z;
    const int c0  = blockIdx.y * NCH;
    const int tx0 = (blockIdx.x % nTX) * TS;
    const int ty0 = (blockIdx.x / nTX) * TS;
    const int t   = threadIdx.x;
    const int HW  = H * W;
    const float* flx = flow + (size_t)b * 2 * HW;
    const float* fly = flx + HW;
    const float* fb  = feat + ((size_t)b * C + c0) * HW;

    for (int i = t; i < WS * WS; i += 256) {
        const int wsy = i / WS, wsx = i - wsy * WS;
        const int gy = ty0 - K + wsy, gx = tx0 - K + wsx;
        float fxr = 1e9f, fyr = 1e9f;
        if (gy >= 0 && gy < H && gx >= 0 && gx < W) {
            const float dxf = flx[(size_t)gy * W + gx];
            const float dyf = fly[(size_t)gy * W + gx];
            if (fabsf(dxf) <= THR && fabsf(dyf) <= THR) {
                fxr = dxf + (float)(gx - tx0);
                fyr = dyf + (float)(gy - ty0);
            }
        }
        s_fx[wsy * SSTR + wsx] = fxr;
        s_fy[wsy * SSTR + wsx] = fyr;
    }
    __syncthreads();

    const int r  = t / TPR;
    const int x0 = (t % TPR) * RUN;

    int n = 0;
    unsigned short* hl = s_hit + t * HCAP;
#pragma unroll
    for (int dy = 0; dy <= 2 * K; ++dy) {
        const int wsy = r + dy;
        const int base = wsy * SSTR + x0;
#pragma unroll
        for (int dxx = 0; dxx < RUN + 2 * K; ++dxx) {
            const float fyr = s_fy[base + dxx];
            const float fxr = s_fx[base + dxx];
            const float ty = fyr - (float)r;
            const float ux = fxr - (float)x0;
            if (ty > -1.f && ty < 1.f && ux > -1.f && ux < (float)RUN &&
                n < HCAP) {
                hl[n] = (unsigned short)((wsy << 6) | (x0 + dxx));
                ++n;
            }
        }
    }

    float acc[RUN][NCH];
    float cnt[RUN];
#pragma unroll
    for (int m = 0; m < RUN; ++m) {
        cnt[m] = 0.f;
#pragma unroll
        for (int ch = 0; ch < NCH; ++ch) acc[m][ch] = 0.f;
    }

    for (int k = 0; k < n; ++k) {
        const int idx = hl[k];
        const int wsy = idx >> 6, wsx = idx & 63;
        const float fxr = s_fx[wsy * SSTR + wsx];
        const float fyr = s_fy[wsy * SSTR + wsx];
        const float wy = 1.f - fabsf(fyr - (float)r);
        const float ux = fxr - (float)x0;
        const int gsy = ty0 - K + wsy, gsx = tx0 - K + wsx;
        const float* fp = fb + (size_t)gsy * W + gsx;
        float wm[RUN];
#pragma unroll
        for (int m = 0; m < RUN; ++m) {
            wm[m] = fmaxf(0.f, 1.f - fabsf(ux - (float)m)) * wy;
            cnt[m] += wm[m];
        }
#pragma unroll
        for (int ch = 0; ch < NCH; ++ch) {
            const float f = fp[(size_t)ch * HW];
#pragma unroll
            for (int m = 0; m < RUN; ++m)
                acc[m][ch] = fmaf(wm[m], f, acc[m][ch]);
        }
    }

    const int has = *oflag;
    const int gy = ty0 + r;
    const size_t rowoff = (size_t)gy * W + (tx0 + x0);
    float inv[RUN];
#pragma unroll
    for (int m = 0; m < RUN; ++m) {
        float cv = cnt[m];
        if (has) cv += cnt_ov[(size_t)b * HW + rowoff + m];
        inv[m] = 1.f / ((cv == 0.f) ? 1.f : cv);
    }
#pragma unroll
    for (int ch = 0; ch < NCH; ++ch) {
        const size_t go = ((size_t)b * C + (c0 + ch)) * HW + rowoff;
        if constexpr (RUN == 4) {
            float vv[4];
#pragma unroll
            for (int m = 0; m < 4; ++m) {
                float x = acc[m][ch];
                if (has) x += out[go + m];
                vv[m] = x * inv[m];
            }
            float4 v4 = {vv[0], vv[1], vv[2], vv[3]};
            *reinterpret_cast<float4*>(out + go) = v4;
        } else {
            float x = acc[0][ch];
            if (has) x += out[go];
            out[go] = x * inv[0];
        }
    }
}

extern "C" void kernel_launch(void* const* d_in, const int* in_sizes, int n_in,
                              void* d_out, int out_size, void* d_ws, size_t ws_size,
                              hipStream_t stream) {
    (void)in_sizes; (void)n_in; (void)ws_size;

    const float* img  = (const float*)d_in[0];
    const float* flow = (const float*)d_in[1];
    const float* P[4][6];
    for (int i = 0; i < 4; ++i)
        for (int j = 0; j < 6; ++j)
            P[i][j] = (const float*)d_in[2 + 6 * i + j];

    const int Bn = 16;
    float* ws = (float*)d_ws;
    float* bufA = ws;                       // 16M floats
    float* bufB = ws + 16777216;            // 16M floats
    float* flA  = ws + 33554432;            // 2M floats
    float* flB  = ws + 35651584;            // 512K floats
    float* cnt  = ws + 36175872;            // 1M floats (outlier cnt overlay)
    int*   flag = (int*)(ws + 37224448);    // outlier-present flag
    float* out  = (float*)d_out;

    hipMemsetAsync(d_out, 0, (size_t)out_size * sizeof(float), stream);

    auto halve = [&](const float* in, float* o, int Hi, int Wi) {
        const int Ho = Hi / 2, Wo = Wi / 2;
        const int total = Bn * 2 * Ho * Wo;
        hipLaunchKernelGGL(halve_flow_kernel, dim3(CDIV(total, 256)), dim3(256),
                           0, stream, in, o, Bn * 2, Ho, Wo, Hi, Wi);
    };

    float* p1 = out;
    float* p2 = p1 + (size_t)Bn * 16 * 256 * 256;
    float* p3 = p2 + (size_t)Bn * 32 * 128 * 128;
    float* p4 = p3 + (size_t)Bn * 64 * 64 * 64;

#define CONV(S, TWv, THv, CBv, inp, wi, o, Ci_, Hi_, Wi_, Co_)                 \
    do {                                                                       \
        const int Ho_ = (Hi_) / (S), Wo_ = (Wi_) / (S);                        \
        const int nTX_ = Wo_ / (TWv), nTY_ = Ho_ / (THv);                      \
        hipLaunchKernelGGL((conv3x3_pk_kernel<S, TWv, THv, CBv>),              \
                           dim3(nTX_ * nTY_, (Co_) / 16, Bn), dim3(256), 0,    \
                           stream, inp, P[wi][0 + 3 * ((S) == 1)],             \
                           P[wi][1 + 3 * ((S) == 1)], P[wi][2 + 3 * ((S) == 1)],\
                           o, Ci_, Hi_, Wi_, Co_, Ho_, Wo_, nTX_);             \
    } while (0)

    // ---- level 1
    CONV(2, 32, 32, 1, img,  0, bufA, 3, 512, 512, 16);
    CONV(1, 32, 32, 2, bufA, 0, bufB, 16, 256, 256, 16);
    halve(flow, flA, 512, 512);
    {
        const int C = 16, H = 256, W = 256;
        hipMemsetAsync(cnt, 0, (size_t)Bn * H * W * sizeof(float), stream);
        hipMemsetAsync(flag, 0, sizeof(int), stream);
        hipLaunchKernelGGL(splat_outlier_kernel, dim3(CDIV(Bn * H * W, 256)),
                           dim3(256), 0, stream, bufB, flA, p1, cnt, flag,
                           Bn, C, H, W, 3.f);
        hipLaunchKernelGGL((splat_gather_kernel<32, 4, 16, 40>),
                           dim3((W / 32) * (H / 32), C / 16, Bn), dim3(256), 0,
                           stream, bufB, flA, cnt, flag, p1, C, H, W, W / 32);
    }

    // ---- level 2
    CONV(2, 32, 32, 1, bufB, 1, bufA, 16, 256, 256, 32);
    CONV(1, 32, 32, 2, bufA, 1, bufB, 32, 128, 128, 32);
    halve(flA, flB, 256, 256);
    {
        const int C = 32, H = 128, W = 128;
        hipMemsetAsync(cnt, 0, (size_t)Bn * H * W * sizeof(float), stream);
        hipMemsetAsync(flag, 0, sizeof(int), stream);
        hipLaunchKernelGGL(splat_outlier_kernel, dim3(CDIV(Bn * H * W, 256)),
                           dim3(256), 0, stream, bufB, flB, p2, cnt, flag,
                           Bn, C, H, W, 2.f);
        hipLaunchKernelGGL((splat_gather_kernel<32, 3, 16, 40>),
                           dim3((W / 32) * (H / 32), C / 16, Bn), dim3(256), 0,
                           stream, bufB, flB, cnt, flag, p2, C, H, W, W / 32);
    }

    // ---- level 3
    CONV(2, 32, 16, 1, bufB, 2, bufA, 32, 128, 128, 64);
    CONV(1, 32, 16, 2, bufA, 2, bufB, 64, 64, 64, 64);
    halve(flB, flA, 128, 128);
    {
        const int C = 64, H = 64, W = 64;
        hipMemsetAsync(cnt, 0, (size_t)Bn * H * W * sizeof(float), stream);
        hipMemsetAsync(flag, 0, sizeof(int), stream);
        hipLaunchKernelGGL(splat_outlier_kernel, dim3(CDIV(Bn * H * W, 256)),
                           dim3(256), 0, stream, bufB, flA, p3, cnt, flag,
                           Bn, C, H, W, 1.f);
        hipLaunchKernelGGL((splat_gather_kernel<16, 2, 16, 24>),
                           dim3((W / 16) * (H / 16), C / 16, Bn), dim3(256), 0,
                           stream, bufB, flA, cnt, flag, p3, C, H, W, W / 16);
    }

    // ---- level 4
    CONV(2, 16, 16, 1, bufB, 3, bufA, 64, 64, 64, 128);
    CONV(1, 16, 16, 2, bufA, 3, bufB, 128, 32, 32, 128);
    halve(flA, flB, 64, 64);
    {
        const int C = 128, H = 32, W = 32;
        hipMemsetAsync(cnt, 0, (size_t)Bn * H * W * sizeof(float), stream);
        hipMemsetAsync(flag, 0, sizeof(int), stream);
        hipLaunchKernelGGL(splat_outlier_kernel, dim3(CDIV(Bn * H * W, 256)),
                           dim3(256), 0, stream, bufB, flB, p4, cnt, flag,
                           Bn, C, H, W, 1.f);
        hipLaunchKernelGGL((splat_gather_kernel<16, 2, 16, 24>),
                           dim3((W / 16) * (H / 16), C / 16, Bn), dim3(256), 0,
                           stream, bufB, flB, cnt, flag, p4, C, H, W, W / 16);
    }
#undef CONV
}

// Round 7
// 1023.451 us; speedup vs baseline: 2.2998x; 1.1462x over previous
//
#include <hip/hip_runtime.h>

#define CDIV(a, b) (((a) + (b) - 1) / (b))

typedef float __attribute__((ext_vector_type(2))) f32x2;
typedef float __attribute__((ext_vector_type(4))) f32x4;

// Packed fp32 FMA: d = a*b + d (per 32-bit half). MI355X full fp32 rate
// (157 TF) is only reachable via VOP3P packed math; scalar v_fmac = half.
__device__ __forceinline__ void pk_fma(f32x2& d, f32x2 a, f32x2 b) {
    asm("v_pk_fma_f32 %0, %1, %2, %0" : "+v"(d) : "v"(a), "v"(b));
}

// Native fp32 atomic add for GLOBAL memory (outlier path only; ~never taken).
__device__ __forceinline__ void fadd_native(float* p, float v) {
    unsafeAtomicAdd(p, v);
}

// ---------------------------------------------------------------------------
// Conv 3x3 pad1 stride{1,2} + bias + PReLU, packed-channel version.
// (unchanged from round 6 — gets its own profiling round next)
// ---------------------------------------------------------------------------
template <int STRIDE, int TW, int TH, int CB>
__global__ __launch_bounds__(256)
void conv3x3_pk_kernel(const float* __restrict__ in,
                       const float* __restrict__ wgt,
                       const float* __restrict__ bias,
                       const float* __restrict__ alpha,
                       float* __restrict__ out,
                       int Ci, int Hi, int Wi, int Co, int Ho, int Wo,
                       int nTX) {
    constexpr int KO  = 16;
    constexpr int PX  = TW / 16, PY = TH / 16;
    constexpr int ISX = TW * STRIDE + 2;
    constexpr int ISY = TH * STRIDE + 2;
    constexpr int ISS = ISX * ISY;
    constexpr int NST = (CB * ISS + 255) / 256;       // staging regs/thread
    constexpr int NWT = (CB * 9 * KO + 255) / 256;    // weight regs/thread
    __shared__ float s_in[CB * ISS];
    __shared__ __align__(16) float s_wt[CB * 9 * KO]; // [p][k][ko]

    const int b   = blockIdx.z;
    const int co0 = blockIdx.y * KO;
    const int tX  = (blockIdx.x % nTX) * TW;
    const int tY  = (blockIdx.x / nTX) * TH;
    const int t   = threadIdx.x;
    const int tcx = t & 15, tcy = t >> 4;
    const int ox0 = PX * tcx, oy0 = PY * tcy;
    const int HiWi = Hi * Wi;

    int  poff[NST];
    bool pval[NST];
    const int ix0 = tX * STRIDE - 1, iy0 = tY * STRIDE - 1;
#pragma unroll
    for (int s = 0; s < NST; ++s) {
        const int i = t + s * 256;
        int off = 0; bool v = false;
        if (i < CB * ISS) {
            const int p = i / ISS, j = i - p * ISS;
            const int r = j / ISX, c = j - r * ISX;
            const int gy = iy0 + r, gx = ix0 + c;
            v = (gy >= 0) && (gy < Hi) && (gx >= 0) && (gx < Wi);
            off = v ? (p * HiWi + gy * Wi + gx) : 0;
        }
        poff[s] = off; pval[s] = v;
    }
    int  wofs[NWT], wdst[NWT];
    bool wvs[NWT];
#pragma unroll
    for (int s = 0; s < NWT; ++s) {
        const int j = t + s * 256;
        bool v = j < CB * 9 * KO;
        int ofs = 0, dst = 0;
        if (v) {
            const int p = j / (9 * KO), rem = j - p * 9 * KO;
            const int k = rem / KO, ko = rem - k * KO;
            ofs = ((co0 + ko) * Ci + p) * 9 + k;
            dst = (p * 9 + k) * KO + ko;
        }
        wofs[s] = ofs; wdst[s] = dst; wvs[s] = v;
    }

    f32x2 acc2[KO / 2][PY][PX];
#pragma unroll
    for (int cp = 0; cp < KO / 2; ++cp)
#pragma unroll
        for (int dy = 0; dy < PY; ++dy)
#pragma unroll
            for (int dx = 0; dx < PX; ++dx) acc2[cp][dy][dx] = (f32x2){0.f, 0.f};

    const float* inb = in + (size_t)b * Ci * HiWi;

    float rs[NST], rw[NWT];
#pragma unroll
    for (int s = 0; s < NST; ++s) rs[s] = pval[s] ? inb[poff[s]] : 0.f;
#pragma unroll
    for (int s = 0; s < NWT; ++s) rw[s] = wvs[s] ? wgt[wofs[s]] : 0.f;

    const int bx = ox0 * STRIDE, by = oy0 * STRIDE;

    for (int ci = 0; ci < Ci; ci += CB) {
        __syncthreads();
#pragma unroll
        for (int s = 0; s < NST; ++s) {
            const int i = t + s * 256;
            if (i < CB * ISS) s_in[i] = rs[s];
        }
#pragma unroll
        for (int s = 0; s < NWT; ++s)
            if (wvs[s]) s_wt[wdst[s]] = rw[s];
        if (ci + CB < Ci) {
            const float* nb = inb + (size_t)(ci + CB) * HiWi;
            const int w9 = (ci + CB) * 9;
#pragma unroll
            for (int s = 0; s < NST; ++s) rs[s] = pval[s] ? nb[poff[s]] : 0.f;
#pragma unroll
            for (int s = 0; s < NWT; ++s)
                rw[s] = wvs[s] ? wgt[wofs[s] + w9] : 0.f;
        }
        __syncthreads();

#pragma unroll
        for (int p = 0; p < CB; ++p) {
            const float* sp = s_in + p * ISS;
#pragma unroll
            for (int ky = 0; ky < 3; ++ky)
#pragma unroll
                for (int kx = 0; kx < 3; ++kx) {
                    const int k = ky * 3 + kx;
                    f32x2 t2[PY][PX];
#pragma unroll
                    for (int dy = 0; dy < PY; ++dy)
#pragma unroll
                        for (int dx = 0; dx < PX; ++dx) {
                            const float tv =
                                sp[(by + dy * STRIDE + ky) * ISX + bx +
                                   dx * STRIDE + kx];
                            t2[dy][dx] = (f32x2){tv, tv};
                        }
                    const float* wb = s_wt + (p * 9 + k) * KO;
#pragma unroll
                    for (int kq = 0; kq < KO / 4; ++kq) {
                        const f32x4 w4 =
                            *reinterpret_cast<const f32x4*>(wb + 4 * kq);
                        const f32x2 wlo = {w4[0], w4[1]};
                        const f32x2 whi = {w4[2], w4[3]};
#pragma unroll
                        for (int dy = 0; dy < PY; ++dy)
#pragma unroll
                            for (int dx = 0; dx < PX; ++dx) {
                                pk_fma(acc2[2 * kq][dy][dx], t2[dy][dx], wlo);
                                pk_fma(acc2[2 * kq + 1][dy][dx], t2[dy][dx], whi);
                            }
                    }
                }
        }
    }

#pragma unroll
    for (int cp = 0; cp < KO / 2; ++cp)
#pragma unroll
        for (int h = 0; h < 2; ++h) {
            const int co = co0 + 2 * cp + h;
            const float bv = bias[co], av = alpha[co];
#pragma unroll
            for (int dy = 0; dy < PY; ++dy) {
                const int oy = tY + oy0 + dy;
#pragma unroll
                for (int dx = 0; dx < PX; ++dx) {
                    const int ox = tX + ox0 + dx;
                    float v = acc2[cp][dy][dx][h] + bv;
                    v = v >= 0.f ? v : av * v;
                    out[(((size_t)b * Co + co) * Ho + oy) * Wo + ox] = v;
                }
            }
        }
}

// ---------------------------------------------------------------------------
// flow halving: 2x2 mean * 0.5 == sum * 0.125
// ---------------------------------------------------------------------------
__global__ void halve_flow_kernel(const float* __restrict__ in,
                                  float* __restrict__ out,
                                  int BC, int Ho, int Wo, int Hi, int Wi) {
    const int idx = blockIdx.x * blockDim.x + threadIdx.x;
    const int total = BC * Ho * Wo;
    if (idx >= total) return;
    const int wo = idx % Wo;
    int t = idx / Wo;
    const int ho = t % Ho;
    const int bc = t / Ho;
    const float* p = in + ((size_t)bc * Hi + 2 * ho) * Wi + 2 * wo;
    out[idx] = (p[0] + p[1] + p[Wi] + p[Wi + 1]) * 0.125f;
}

// ---------------------------------------------------------------------------
// Outlier splat pre-pass: sources with |flow| > thr go through device atomics
// into the num(=out)/cnt overlay. No flag: the gather detects overlay pixels
// via cnt != 0 per-pixel (exact: cnt==0 <=> all overlay weights 0 => num 0).
// thr MUST equal (float)(K-1) of the matching gather kernel.
// ---------------------------------------------------------------------------
__global__ void splat_outlier_kernel(const float* __restrict__ feat,
                                     const float* __restrict__ flow,
                                     float* __restrict__ num,
                                     float* __restrict__ cnt,
                                     int B, int C, int H, int W, float thr) {
    const int HW = H * W;
    const int idx = blockIdx.x * blockDim.x + threadIdx.x;
    if (idx >= B * HW) return;
    const int b = idx / HW, px = idx - b * HW;
    const int y = px / W, x = px - y * W;
    const float dx = flow[(size_t)b * 2 * HW + px];
    const float dy = flow[(size_t)b * 2 * HW + HW + px];
    if (fabsf(dx) <= thr && fabsf(dy) <= thr) return;   // fast-path source
    const float fx = dx + (float)x, fy = dy + (float)y;
    const float x0f = floorf(fx), y0f = floorf(fy);
    const int x0 = (int)x0f, y0 = (int)y0f;
    const float ax = fx - x0f, ay = fy - y0f;
    const float w[4] = {(1.f - ax) * (1.f - ay), ax * (1.f - ay),
                        (1.f - ax) * ay,         ax * ay};
    const int cx[4] = {x0, x0 + 1, x0, x0 + 1};
    const int cy[4] = {y0, y0, y0 + 1, y0 + 1};
    float* cb = cnt + (size_t)b * HW;
    for (int k = 0; k < 4; ++k) {
        if (cx[k] < 0 || cx[k] >= W || cy[k] < 0 || cy[k] >= H) continue;
        if (w[k] == 0.f) continue;
        const size_t d = (size_t)cy[k] * W + cx[k];
        fadd_native(cb + d, w[k]);
        for (int c = 0; c < C; ++c)
            fadd_native(num + ((size_t)b * C + c) * HW + d,
                        feat[((size_t)b * C + c) * HW + px] * w[k]);
    }
}

// ---------------------------------------------------------------------------
// GATHER splat v2: zero atomics, channel-streamed LDS staging.
//  - phase 0: stage tile-relative (fx,fy) interleaved in LDS (b64 reads later);
//    outliers/out-of-image staged 1e9 -> fail all hit tests (exact via
//    splat_outlier_kernel overlay)
//  - phase 1: scan (2K+1)x(RUN+2K) candidates once, compact hits/thread
//  - phase 2: for each channel: stage WS*WS feature plane in LDS (coalesced,
//    register-double-buffered), walk own hits reading coords+feature from LDS,
//    accumulate in registers; divide and plain-store
//  - overlay: read cnt_ov per dest pixel; only where !=0 read out[] (rare)
// ---------------------------------------------------------------------------
template <int TS, int K, int NCH, int HCAP>
__global__ __launch_bounds__(256)
void splat_gather2_kernel(const float* __restrict__ feat,
                          const float* __restrict__ flow,
                          const float* __restrict__ cnt_ov,
                          float* __restrict__ out,
                          int C, int H, int W, int nTX) {
    constexpr int WS   = TS + 2 * K;
    constexpr int SSTR = WS + 1;
    constexpr int RUN  = TS * TS / 256;   // dest px per thread (4 or 1)
    constexpr int TPR  = TS / RUN;
    constexpr int NSF  = (WS * WS + 255) / 256;
    constexpr float THR = (float)(K - 1);
    __shared__ __align__(8) float s_xy[2 * WS * SSTR];  // interleaved fx,fy
    __shared__ float s_feat[WS * SSTR];
    __shared__ unsigned short s_hit[256 * HCAP];

    const int b   = blockIdx.z;
    const int c0  = blockIdx.y * NCH;
    const int tx0 = (blockIdx.x % nTX) * TS;
    const int ty0 = (blockIdx.x / nTX) * TS;
    const int t   = threadIdx.x;
    const int HW  = H * W;
    const float* flx = flow + (size_t)b * 2 * HW;
    const float* fly = flx + HW;
    const float* fb  = feat + ((size_t)b * C + c0) * HW;

    // ---- phase 0: coords + per-thread staging slots
    int  foff[NSF], sdst[NSF];
    bool fval[NSF];
#pragma unroll
    for (int s = 0; s < NSF; ++s) {
        const int i = t + s * 256;
        foff[s] = 0; sdst[s] = 0; fval[s] = false;
        if (i < WS * WS) {
            const int wsy = i / WS, wsx = i - wsy * WS;
            const int gy = ty0 - K + wsy, gx = tx0 - K + wsx;
            const int off = wsy * SSTR + wsx;
            sdst[s] = off;
            float fxr = 1e9f, fyr = 1e9f;
            if (gy >= 0 && gy < H && gx >= 0 && gx < W) {
                fval[s] = true;
                foff[s] = gy * W + gx;
                const float dxf = flx[foff[s]];
                const float dyf = fly[foff[s]];
                if (fabsf(dxf) <= THR && fabsf(dyf) <= THR) {
                    fxr = dxf + (float)(gx - tx0);
                    fyr = dyf + (float)(gy - ty0);
                }
            }
            *reinterpret_cast<f32x2*>(&s_xy[2 * off]) = (f32x2){fxr, fyr};
        }
    }
    __syncthreads();

    const int r  = t / TPR;
    const int x0 = (t % TPR) * RUN;

    // ---- phase 1: candidate scan -> hit list (once, reused for all channels)
    int n = 0;
    unsigned short* hl = s_hit + t * HCAP;
#pragma unroll
    for (int dy = 0; dy <= 2 * K; ++dy) {
        const int wsy = r + dy;
        const int base = wsy * SSTR + x0;
#pragma unroll
        for (int dxx = 0; dxx < RUN + 2 * K; ++dxx) {
            const f32x2 xy =
                *reinterpret_cast<const f32x2*>(&s_xy[2 * (base + dxx)]);
            const float ty = xy[1] - (float)r;
            const float ux = xy[0] - (float)x0;
            if (ty > -1.f && ty < 1.f && ux > -1.f && ux < (float)RUN &&
                n < HCAP) {
                hl[n] = (unsigned short)((wsy << 6) | (x0 + dxx));
                ++n;
            }
        }
    }

    // ---- overlay per-pixel counts (coalesced; rare nonzero)
    const int gyd = ty0 + r;
    const size_t rowoff = (size_t)gyd * W + (tx0 + x0);
    float cv_ov[RUN];
#pragma unroll
    for (int m = 0; m < RUN; ++m)
        cv_ov[m] = cnt_ov[(size_t)b * HW + rowoff + m];

    // ---- phase 2: channel-streamed accumulate
    float rs[NSF];
#pragma unroll
    for (int s = 0; s < NSF; ++s) rs[s] = fval[s] ? fb[foff[s]] : 0.f;

    float inv[RUN];
#pragma unroll
    for (int ch = 0; ch < NCH; ++ch) {
        __syncthreads();   // walkers done with previous channel's s_feat
#pragma unroll
        for (int s = 0; s < NSF; ++s)
            if (t + s * 256 < WS * WS) s_feat[sdst[s]] = rs[s];
        if (ch + 1 < NCH) {
            const float* nfb = fb + (size_t)(ch + 1) * HW;
#pragma unroll
            for (int s = 0; s < NSF; ++s) rs[s] = fval[s] ? nfb[foff[s]] : 0.f;
        }
        __syncthreads();

        float a[RUN];
        float cw[RUN];
#pragma unroll
        for (int m = 0; m < RUN; ++m) { a[m] = 0.f; cw[m] = 0.f; }
        for (int k = 0; k < n; ++k) {
            const int idx = hl[k];
            const int off = (idx >> 6) * SSTR + (idx & 63);
            const f32x2 xy = *reinterpret_cast<const f32x2*>(&s_xy[2 * off]);
            const float f = s_feat[off];
            const float wy = 1.f - fabsf(xy[1] - (float)r);
            const float ux = xy[0] - (float)x0;
#pragma unroll
            for (int m = 0; m < RUN; ++m) {
                const float wm = fmaxf(0.f, 1.f - fabsf(ux - (float)m)) * wy;
                a[m] = fmaf(wm, f, a[m]);
                if (ch == 0) cw[m] += wm;
            }
        }
        if (ch == 0) {
#pragma unroll
            for (int m = 0; m < RUN; ++m) {
                const float cv = cw[m] + cv_ov[m];
                inv[m] = 1.f / ((cv == 0.f) ? 1.f : cv);
            }
        }

        const size_t go = ((size_t)b * C + (c0 + ch)) * HW + rowoff;
        if constexpr (RUN == 4) {
            float vv[4];
#pragma unroll
            for (int m = 0; m < 4; ++m) {
                float x = a[m];
                if (cv_ov[m] != 0.f) x += out[go + m];   // rare overlay pixels
                vv[m] = x * inv[m];
            }
            float4 v4 = {vv[0], vv[1], vv[2], vv[3]};
            *reinterpret_cast<float4*>(out + go) = v4;
        } else {
            float x = a[0];
            if (cv_ov[0] != 0.f) x += out[go];
            out[go] = x * inv[0];
        }
    }
}

extern "C" void kernel_launch(void* const* d_in, const int* in_sizes, int n_in,
                              void* d_out, int out_size, void* d_ws, size_t ws_size,
                              hipStream_t stream) {
    (void)in_sizes; (void)n_in; (void)ws_size;

    const float* img  = (const float*)d_in[0];
    const float* flow = (const float*)d_in[1];
    const float* P[4][6];
    for (int i = 0; i < 4; ++i)
        for (int j = 0; j < 6; ++j)
            P[i][j] = (const float*)d_in[2 + 6 * i + j];

    const int Bn = 16;
    float* ws = (float*)d_ws;
    float* bufA = ws;                       // 16M floats
    float* bufB = ws + 16777216;            // 16M floats
    float* flA  = ws + 33554432;            // 2M floats
    float* flB  = ws + 35651584;            // 512K floats
    float* cnt  = ws + 36175872;            // 1M floats (outlier cnt overlay)
    float* out  = (float*)d_out;

    hipMemsetAsync(d_out, 0, (size_t)out_size * sizeof(float), stream);

    auto halve = [&](const float* in, float* o, int Hi, int Wi) {
        const int Ho = Hi / 2, Wo = Wi / 2;
        const int total = Bn * 2 * Ho * Wo;
        hipLaunchKernelGGL(halve_flow_kernel, dim3(CDIV(total, 256)), dim3(256),
                           0, stream, in, o, Bn * 2, Ho, Wo, Hi, Wi);
    };

    float* p1 = out;
    float* p2 = p1 + (size_t)Bn * 16 * 256 * 256;
    float* p3 = p2 + (size_t)Bn * 32 * 128 * 128;
    float* p4 = p3 + (size_t)Bn * 64 * 64 * 64;

#define CONV(S, TWv, THv, CBv, inp, wi, o, Ci_, Hi_, Wi_, Co_)                 \
    do {                                                                       \
        const int Ho_ = (Hi_) / (S), Wo_ = (Wi_) / (S);                        \
        const int nTX_ = Wo_ / (TWv), nTY_ = Ho_ / (THv);                      \
        hipLaunchKernelGGL((conv3x3_pk_kernel<S, TWv, THv, CBv>),              \
                           dim3(nTX_ * nTY_, (Co_) / 16, Bn), dim3(256), 0,    \
                           stream, inp, P[wi][0 + 3 * ((S) == 1)],             \
                           P[wi][1 + 3 * ((S) == 1)], P[wi][2 + 3 * ((S) == 1)],\
                           o, Ci_, Hi_, Wi_, Co_, Ho_, Wo_, nTX_);             \
    } while (0)

#define SPLAT(TSv, Kv, NCHv, HCAPv, featp, flp, op, C_, H_, W_, thr)           \
    do {                                                                       \
        hipMemsetAsync(cnt, 0, (size_t)Bn * (H_) * (W_) * sizeof(float),       \
                       stream);                                                \
        hipLaunchKernelGGL(splat_outlier_kernel,                               \
                           dim3(CDIV(Bn * (H_) * (W_), 256)), dim3(256), 0,    \
                           stream, featp, flp, op, cnt, Bn, C_, H_, W_, thr);  \
        hipLaunchKernelGGL((splat_gather2_kernel<TSv, Kv, NCHv, HCAPv>),       \
                           dim3(((W_) / (TSv)) * ((H_) / (TSv)),               \
                                (C_) / (NCHv), Bn),                            \
                           dim3(256), 0, stream, featp, flp, cnt, op,          \
                           C_, H_, W_, (W_) / (TSv));                          \
    } while (0)

    // ---- level 1
    CONV(2, 32, 32, 1, img,  0, bufA, 3, 512, 512, 16);
    CONV(1, 32, 32, 2, bufA, 0, bufB, 16, 256, 256, 16);
    halve(flow, flA, 512, 512);
    SPLAT(32, 4, 16, 32, bufB, flA, p1, 16, 256, 256, 3.f);

    // ---- level 2
    CONV(2, 32, 32, 1, bufB, 1, bufA, 16, 256, 256, 32);
    CONV(1, 32, 32, 2, bufA, 1, bufB, 32, 128, 128, 32);
    halve(flA, flB, 256, 256);
    SPLAT(32, 3, 16, 32, bufB, flB, p2, 32, 128, 128, 2.f);

    // ---- level 3
    CONV(2, 32, 16, 1, bufB, 2, bufA, 32, 128, 128, 64);
    CONV(1, 32, 16, 2, bufA, 2, bufB, 64, 64, 64, 64);
    halve(flB, flA, 128, 128);
    SPLAT(16, 2, 16, 16, bufB, flA, p3, 64, 64, 64, 1.f);

    // ---- level 4
    CONV(2, 16, 16, 1, bufB, 3, bufA, 64, 64, 64, 128);
    CONV(1, 16, 16, 2, bufA, 3, bufB, 128, 32, 32, 128);
    halve(flA, flB, 64, 64);
    SPLAT(16, 2, 16, 16, bufB, flB, p4, 128, 32, 32, 1.f);

#undef CONV
#undef SPLAT
}